// Round 4
// baseline (462.519 us; speedup 1.0000x reference)
//
#include <hip/hip_runtime.h>

typedef __attribute__((ext_vector_type(8))) short bf16x8;
typedef __attribute__((ext_vector_type(4))) float f32x4;
typedef __attribute__((ext_vector_type(4))) unsigned short u16x4;

#define DEVI static __device__ __forceinline__

DEVI float bf2f(unsigned short u) {
    union { unsigned int ui; float f; } c; c.ui = ((unsigned int)u) << 16; return c.f;
}
DEVI unsigned short f2bf(float f) {
    union { float f; unsigned int ui; } c; c.f = f;
    unsigned int u = c.ui;
    u += 0x7FFFu + ((u >> 16) & 1u);
    return (unsigned short)(u >> 16);
}

#define NRES 320
#define NN   102400
#define CCH  128
#define NPAD 344
#define PPAD 168

#define LOG2E 1.4426950408889634f
#define QSCALE (0.17677669529663687f * 1.4426950408889634f)

// ---------------- Kernel 1: fused LN + bterm + qkvg projections ----------------
__global__ __launch_bounds__(256) void k_projln(
    const float* __restrict__ x2d, const float* __restrict__ ln_g,
    const float* __restrict__ ln_b, const float* __restrict__ wb,
    const float* __restrict__ wq, const float* __restrict__ wk,
    const float* __restrict__ wv, const float* __restrict__ wg,
    const float* __restrict__ bg,
    unsigned short* __restrict__ qkvg, float* __restrict__ bterm)
{
    __shared__ unsigned short A[128][136];
    __shared__ unsigned short Bt[128][136];   // Bt[n][k]
    int m0 = blockIdx.x * 128;
    int t = threadIdx.x;
    // --- LayerNorm: 2 threads per row, 64 channels each ---
    int row = t >> 1, half = t & 1;
    const float* xr = x2d + (size_t)(m0 + row) * CCH + half * 64;
    float4 xv[16];
    float s = 0.f, sq = 0.f;
    #pragma unroll
    for (int i = 0; i < 16; ++i) {
        xv[i] = *(const float4*)(xr + i * 4);
        s += (xv[i].x + xv[i].y) + (xv[i].z + xv[i].w);
        sq += (xv[i].x * xv[i].x + xv[i].y * xv[i].y) + (xv[i].z * xv[i].z + xv[i].w * xv[i].w);
    }
    s += __shfl_xor(s, 1, 64); sq += __shfl_xor(sq, 1, 64);
    float mu = s * (1.0f / 128.0f);
    float var = sq * (1.0f / 128.0f) - mu * mu;
    float rstd = rsqrtf(var + 1e-5f);
    float bp0 = 0.f, bp1 = 0.f, bp2 = 0.f, bp3 = 0.f;
    #pragma unroll
    for (int g8 = 0; g8 < 8; ++g8) {
        int c0 = half * 64 + g8 * 8;
        float4 ga = *(const float4*)(ln_g + c0), gb = *(const float4*)(ln_g + c0 + 4);
        float4 ba = *(const float4*)(ln_b + c0), bb = *(const float4*)(ln_b + c0 + 4);
        float4 a = xv[g8 * 2], b = xv[g8 * 2 + 1];
        float xf[8];
        xf[0] = (a.x - mu) * rstd * ga.x + ba.x;
        xf[1] = (a.y - mu) * rstd * ga.y + ba.y;
        xf[2] = (a.z - mu) * rstd * ga.z + ba.z;
        xf[3] = (a.w - mu) * rstd * ga.w + ba.w;
        xf[4] = (b.x - mu) * rstd * gb.x + bb.x;
        xf[5] = (b.y - mu) * rstd * gb.y + bb.y;
        xf[6] = (b.z - mu) * rstd * gb.z + bb.z;
        xf[7] = (b.w - mu) * rstd * gb.w + bb.w;
        #pragma unroll
        for (int z = 0; z < 8; ++z) {
            float4 w = *(const float4*)(wb + (c0 + z) * 4);
            bp0 += xf[z] * w.x; bp1 += xf[z] * w.y;
            bp2 += xf[z] * w.z; bp3 += xf[z] * w.w;
        }
        union { unsigned short u[8]; bf16x8 v; } pk;
        #pragma unroll
        for (int z = 0; z < 8; ++z) pk.u[z] = f2bf(xf[z]);
        *(bf16x8*)(&A[row][c0]) = pk.v;
    }
    bp0 += __shfl_xor(bp0, 1, 64); bp1 += __shfl_xor(bp1, 1, 64);
    bp2 += __shfl_xor(bp2, 1, 64); bp3 += __shfl_xor(bp3, 1, 64);
    if (!half) {
        int r = m0 + row;
        bterm[0 * NN + r] = bp0 * LOG2E; bterm[1 * NN + r] = bp1 * LOG2E;
        bterm[2 * NN + r] = bp2 * LOG2E; bterm[3 * NN + r] = bp3 * LOG2E;
    }
    // --- 4 projection GEMMs, A-tile reused ---
    int wave = t >> 6, lane = t & 63;
    int wr = (wave >> 1) * 64, wc = (wave & 1) * 64;
    int li = lane & 15, lk = (lane >> 4) * 8;
    int rbase = (lane >> 4) * 4;
    const float* Ws[4] = { wq, wk, wv, wg };
    for (int nt = 0; nt < 4; ++nt) {
        if (nt) __syncthreads();
        const float* wsrc = Ws[nt];
        #pragma unroll
        for (int it = 0; it < 16; ++it) {
            int k = it * 8 + (t >> 5);
            int n4 = (t & 31) * 4;
            float4 w = *(const float4*)(wsrc + k * 128 + n4);
            Bt[n4 + 0][k] = f2bf(w.x); Bt[n4 + 1][k] = f2bf(w.y);
            Bt[n4 + 2][k] = f2bf(w.z); Bt[n4 + 3][k] = f2bf(w.w);
        }
        __syncthreads();
        f32x4 acc[4][4] = {};
        #pragma unroll
        for (int kk = 0; kk < 4; ++kk) {
            bf16x8 af[4], bfr[4];
            #pragma unroll
            for (int i = 0; i < 4; ++i) af[i] = *(const bf16x8*)(&A[wr + i * 16 + li][kk * 32 + lk]);
            #pragma unroll
            for (int j = 0; j < 4; ++j) bfr[j] = *(const bf16x8*)(&Bt[wc + j * 16 + li][kk * 32 + lk]);
            __builtin_amdgcn_s_setprio(1);
            #pragma unroll
            for (int i = 0; i < 4; ++i)
                #pragma unroll
                for (int j = 0; j < 4; ++j)
                    acc[i][j] = __builtin_amdgcn_mfma_f32_16x16x32_bf16(af[i], bfr[j], acc[i][j], 0, 0, 0);
            __builtin_amdgcn_s_setprio(0);
        }
        bool isg = (nt == 3), isq = (nt == 0);
        #pragma unroll
        for (int i = 0; i < 4; ++i) {
            #pragma unroll
            for (int j = 0; j < 4; ++j) {
                int col = wc + j * 16 + li;
                int gcol = nt * 128 + col;
                #pragma unroll
                for (int r = 0; r < 4; ++r) {
                    int grow = m0 + wr + i * 16 + rbase + r;
                    float v = acc[i][j][r];
                    if (isg) { v += bg[col]; v = 1.0f / (1.0f + __expf(-v)); }
                    if (isq) v *= QSCALE;
                    qkvg[(size_t)grow * 512 + gcol] = f2bf(v);
                }
            }
        }
    }
}

// ---------------- Kernel 2: fused attention per (m,h) ----------------
__global__ __launch_bounds__(256) __attribute__((amdgpu_waves_per_eu(2)))
void k_attn(
    const unsigned short* __restrict__ qkvg,
    const float* __restrict__ bterm,
    const float* __restrict__ mask,
    unsigned short* __restrict__ opre)
{
    __shared__ unsigned short Kl[320][40];     // K rows [j][dc]
    __shared__ unsigned short VT[32][NPAD];    // V transposed [dc][j]
    __shared__ unsigned short Pl[4][16][PPAD]; // per-wave P, half the j range at a time
    __shared__ float mb[320];
    int bid = blockIdx.x;
    int m = bid >> 2, h = bid & 3;
    int t = threadIdx.x;
    size_t base = (size_t)m * NRES * 512;
    for (int j = t; j < NRES; j += 256) {
        const bf16x8* src = (const bf16x8*)(qkvg + base + (size_t)j * 512 + 128 + h * 32);
        bf16x8* dst = (bf16x8*)(&Kl[j][0]);
        dst[0] = src[0]; dst[1] = src[1]; dst[2] = src[2]; dst[3] = src[3];
    }
    {
        int dc = t & 31, jg = t >> 5;
        #pragma unroll 8
        for (int jj = 0; jj < 40; jj += 2) {
            int j = jg * 40 + jj;
            unsigned short v0 = qkvg[base + (size_t)j * 512 + 256 + h * 32 + dc];
            unsigned short v1 = qkvg[base + (size_t)(j + 1) * 512 + 256 + h * 32 + dc];
            *(unsigned int*)(&VT[dc][j]) = (unsigned int)v0 | ((unsigned int)v1 << 16);
        }
    }
    for (int j = t; j < NRES; j += 256) mb[j] = (100000.0f * LOG2E) * (mask[(size_t)m * NRES + j] - 1.0f);
    __syncthreads();

    int wave = t >> 6, lane = t & 63;
    int li = lane & 15, lg = lane >> 4;
    for (int c = 0; c < 5; ++c) {
        int i0 = wave * 80 + c * 16;
        int i = i0 + li;
        size_t qrow = base + (size_t)i * 512;
        bf16x8 qf = *(const bf16x8*)(qkvg + qrow + h * 32 + lg * 8);
        f32x4 z = {0.f, 0.f, 0.f, 0.f};
        f32x4 st[20];
        __builtin_amdgcn_s_setprio(1);
        #pragma unroll
        for (int jf = 0; jf < 20; ++jf) {
            bf16x8 kf = *(const bf16x8*)(&Kl[jf * 16 + li][lg * 8]);
            st[jf] = __builtin_amdgcn_mfma_f32_16x16x32_bf16(kf, qf, z, 0, 0, 0);
        }
        __builtin_amdgcn_s_setprio(0);
        const float* brow = bterm + (size_t)h * NN + (size_t)i * NRES;
        float mx = -3.0e38f;
        #pragma unroll
        for (int jf = 0; jf < 20; ++jf) {
            int j0 = jf * 16 + lg * 4;
            float4 bb = *(const float4*)(brow + j0);
            float4 mm = *(const float4*)(&mb[j0]);
            st[jf][0] += bb.x + mm.x;
            st[jf][1] += bb.y + mm.y;
            st[jf][2] += bb.z + mm.z;
            st[jf][3] += bb.w + mm.w;
            mx = fmaxf(mx, fmaxf(fmaxf(st[jf][0], st[jf][1]), fmaxf(st[jf][2], st[jf][3])));
        }
        mx = fmaxf(mx, __shfl_xor(mx, 16, 64));
        mx = fmaxf(mx, __shfl_xor(mx, 32, 64));
        float sum = 0.0f;
        f32x4 o0 = {0.f, 0.f, 0.f, 0.f}, o1 = {0.f, 0.f, 0.f, 0.f};
        #pragma unroll
        for (int ph = 0; ph < 2; ++ph) {
            #pragma unroll
            for (int jj = 0; jj < 10; ++jj) {
                int jf = ph * 10 + jj;
                float p0 = __builtin_amdgcn_exp2f(st[jf][0] - mx);
                float p1 = __builtin_amdgcn_exp2f(st[jf][1] - mx);
                float p2 = __builtin_amdgcn_exp2f(st[jf][2] - mx);
                float p3 = __builtin_amdgcn_exp2f(st[jf][3] - mx);
                sum += (p0 + p1) + (p2 + p3);
                unsigned int lo = (unsigned int)f2bf(p0) | ((unsigned int)f2bf(p1) << 16);
                unsigned int hi = (unsigned int)f2bf(p2) | ((unsigned int)f2bf(p3) << 16);
                unsigned int* dst = (unsigned int*)(&Pl[wave][li][jj * 16 + lg * 4]);
                dst[0] = lo; dst[1] = hi;
            }
            __builtin_amdgcn_s_setprio(1);
            #pragma unroll
            for (int kk = 0; kk < 5; ++kk) {
                bf16x8 pf = *(const bf16x8*)(&Pl[wave][li][kk * 32 + lg * 8]);
                bf16x8 va = *(const bf16x8*)(&VT[li][ph * 160 + kk * 32 + lg * 8]);
                bf16x8 vb = *(const bf16x8*)(&VT[16 + li][ph * 160 + kk * 32 + lg * 8]);
                o0 = __builtin_amdgcn_mfma_f32_16x16x32_bf16(va, pf, o0, 0, 0, 0);
                o1 = __builtin_amdgcn_mfma_f32_16x16x32_bf16(vb, pf, o1, 0, 0, 0);
            }
            __builtin_amdgcn_s_setprio(0);
        }
        sum += __shfl_xor(sum, 16, 64);
        sum += __shfl_xor(sum, 32, 64);
        float inv = 1.0f / sum;
        size_t orow = ((size_t)m * NRES + i) * CCH + h * 32;
        #pragma unroll
        for (int df = 0; df < 2; ++df) {
            f32x4 o = df ? o1 : o0;
            int dcb = df * 16 + lg * 4;
            u16x4 gv = *(const u16x4*)(qkvg + qrow + 384 + h * 32 + dcb);
            u16x4 ov;
            #pragma unroll
            for (int r = 0; r < 4; ++r) ov[r] = f2bf(o[r] * inv * bf2f(gv[r]));
            *(u16x4*)(opre + orow + dcb) = ov;
        }
    }
}

// ---------------- Kernel 3: out = opre @ wo + bo (f32 out) ----------------
__global__ __launch_bounds__(256) void k_out(
    const unsigned short* __restrict__ opre, const float* __restrict__ wo,
    const float* __restrict__ bo, float* __restrict__ out)
{
    __shared__ unsigned short A[128][136];
    __shared__ unsigned short Bt[128][136];
    int m0 = blockIdx.x * 128;
    int t = threadIdx.x;
    #pragma unroll
    for (int it = 0; it < 8; ++it) {
        int idx = it * 256 + t;
        int row = idx >> 4, chunk = idx & 15;
        *(bf16x8*)(&A[row][chunk * 8]) = *(const bf16x8*)(opre + (size_t)(m0 + row) * CCH + chunk * 8);
    }
    #pragma unroll
    for (int it = 0; it < 16; ++it) {
        int k = it * 8 + (t >> 5);
        int n4 = (t & 31) * 4;
        float4 w = *(const float4*)(wo + k * 128 + n4);
        Bt[n4 + 0][k] = f2bf(w.x); Bt[n4 + 1][k] = f2bf(w.y);
        Bt[n4 + 2][k] = f2bf(w.z); Bt[n4 + 3][k] = f2bf(w.w);
    }
    __syncthreads();
    int wave = t >> 6, lane = t & 63;
    int wr = (wave >> 1) * 64, wc = (wave & 1) * 64;
    int li = lane & 15, lk = (lane >> 4) * 8;
    f32x4 acc[4][4] = {};
    #pragma unroll
    for (int kk = 0; kk < 4; ++kk) {
        bf16x8 af[4], bfr[4];
        #pragma unroll
        for (int i = 0; i < 4; ++i) af[i] = *(const bf16x8*)(&A[wr + i * 16 + li][kk * 32 + lk]);
        #pragma unroll
        for (int j = 0; j < 4; ++j) bfr[j] = *(const bf16x8*)(&Bt[wc + j * 16 + li][kk * 32 + lk]);
        __builtin_amdgcn_s_setprio(1);
        #pragma unroll
        for (int i = 0; i < 4; ++i)
            #pragma unroll
            for (int j = 0; j < 4; ++j)
                acc[i][j] = __builtin_amdgcn_mfma_f32_16x16x32_bf16(af[i], bfr[j], acc[i][j], 0, 0, 0);
        __builtin_amdgcn_s_setprio(0);
    }
    int rbase = (lane >> 4) * 4;
    #pragma unroll
    for (int i = 0; i < 4; ++i) {
        #pragma unroll
        for (int j = 0; j < 4; ++j) {
            int col = wc + j * 16 + li;
            #pragma unroll
            for (int r = 0; r < 4; ++r) {
                int grow = m0 + wr + i * 16 + rbase + r;
                out[(size_t)grow * CCH + col] = acc[i][j][r] + bo[col];
            }
        }
    }
}

extern "C" void kernel_launch(void* const* d_in, const int* in_sizes, int n_in,
                              void* d_out, int out_size, void* d_ws, size_t ws_size,
                              hipStream_t stream) {
    const float* x2d  = (const float*)d_in[0];
    const float* mask = (const float*)d_in[1];
    const float* ln_g = (const float*)d_in[2];
    const float* ln_b = (const float*)d_in[3];
    const float* wq   = (const float*)d_in[4];
    const float* wk   = (const float*)d_in[5];
    const float* wv   = (const float*)d_in[6];
    const float* wb   = (const float*)d_in[7];
    const float* wg   = (const float*)d_in[8];
    const float* bg   = (const float*)d_in[9];
    const float* wo   = (const float*)d_in[10];
    const float* bo   = (const float*)d_in[11];
    float* out = (float*)d_out;

    char* ws = (char*)d_ws;
    unsigned short* opre  = (unsigned short*)ws;                                 // 26,214,400 B
    unsigned short* qkvg  = (unsigned short*)(ws + 26214400);                    // 104,857,600 B
    float*          bterm = (float*)(ws + 26214400 + 104857600);                 // 1,638,400 B

    if (ws_size < (size_t)(26214400 + 104857600 + 1638400)) return;

    k_projln<<<800, 256, 0, stream>>>(x2d, ln_g, ln_b, wb, wq, wk, wv, wg, bg, qkvg, bterm);
    k_attn<<<1280, 256, 0, stream>>>(qkvg, bterm, mask, opre);
    k_out<<<800, 256, 0, stream>>>(opre, wo, bo, out);
}

// Round 5
// 374.984 us; speedup vs baseline: 1.2334x; 1.2334x over previous
//
#include <hip/hip_runtime.h>

typedef __attribute__((ext_vector_type(8))) short bf16x8;
typedef __attribute__((ext_vector_type(4))) float f32x4;
typedef __attribute__((ext_vector_type(4))) unsigned short u16x4;

#define DEVI static __device__ __forceinline__

DEVI float bf2f(unsigned short u) {
    union { unsigned int ui; float f; } c; c.ui = ((unsigned int)u) << 16; return c.f;
}
DEVI unsigned short f2bf(float f) {
    union { float f; unsigned int ui; } c; c.f = f;
    unsigned int u = c.ui;
    u += 0x7FFFu + ((u >> 16) & 1u);
    return (unsigned short)(u >> 16);
}

#define NRES 320
#define NN   102400
#define CCH  128
#define NPAD 344
#define PPAD 168

#define LOG2E 1.4426950408889634f
#define QSCALE (0.17677669529663687f * 1.4426950408889634f)

// ---------------- Kernel 1: fused LN + bterm + qkvg projections ----------------
__global__ __launch_bounds__(256) void k_projln(
    const float* __restrict__ x2d, const float* __restrict__ ln_g,
    const float* __restrict__ ln_b, const float* __restrict__ wb,
    const float* __restrict__ wq, const float* __restrict__ wk,
    const float* __restrict__ wv, const float* __restrict__ wg,
    const float* __restrict__ bg,
    unsigned short* __restrict__ qkvg, float* __restrict__ bterm)
{
    __shared__ unsigned short A[128][136];
    __shared__ unsigned short Bt[128][136];   // Bt[n][k]
    int m0 = blockIdx.x * 128;
    int t = threadIdx.x;
    // --- LayerNorm: 2 threads per row, 64 channels each ---
    int row = t >> 1, half = t & 1;
    const float* xr = x2d + (size_t)(m0 + row) * CCH + half * 64;
    float4 xv[16];
    float s = 0.f, sq = 0.f;
    #pragma unroll
    for (int i = 0; i < 16; ++i) {
        xv[i] = *(const float4*)(xr + i * 4);
        s += (xv[i].x + xv[i].y) + (xv[i].z + xv[i].w);
        sq += (xv[i].x * xv[i].x + xv[i].y * xv[i].y) + (xv[i].z * xv[i].z + xv[i].w * xv[i].w);
    }
    s += __shfl_xor(s, 1, 64); sq += __shfl_xor(sq, 1, 64);
    float mu = s * (1.0f / 128.0f);
    float var = sq * (1.0f / 128.0f) - mu * mu;
    float rstd = rsqrtf(var + 1e-5f);
    float bp0 = 0.f, bp1 = 0.f, bp2 = 0.f, bp3 = 0.f;
    #pragma unroll
    for (int g8 = 0; g8 < 8; ++g8) {
        int c0 = half * 64 + g8 * 8;
        float4 ga = *(const float4*)(ln_g + c0), gb = *(const float4*)(ln_g + c0 + 4);
        float4 ba = *(const float4*)(ln_b + c0), bb = *(const float4*)(ln_b + c0 + 4);
        float4 a = xv[g8 * 2], b = xv[g8 * 2 + 1];
        float xf[8];
        xf[0] = (a.x - mu) * rstd * ga.x + ba.x;
        xf[1] = (a.y - mu) * rstd * ga.y + ba.y;
        xf[2] = (a.z - mu) * rstd * ga.z + ba.z;
        xf[3] = (a.w - mu) * rstd * ga.w + ba.w;
        xf[4] = (b.x - mu) * rstd * gb.x + bb.x;
        xf[5] = (b.y - mu) * rstd * gb.y + bb.y;
        xf[6] = (b.z - mu) * rstd * gb.z + bb.z;
        xf[7] = (b.w - mu) * rstd * gb.w + bb.w;
        #pragma unroll
        for (int z = 0; z < 8; ++z) {
            float4 w = *(const float4*)(wb + (c0 + z) * 4);
            bp0 += xf[z] * w.x; bp1 += xf[z] * w.y;
            bp2 += xf[z] * w.z; bp3 += xf[z] * w.w;
        }
        union { unsigned short u[8]; bf16x8 v; } pk;
        #pragma unroll
        for (int z = 0; z < 8; ++z) pk.u[z] = f2bf(xf[z]);
        *(bf16x8*)(&A[row][c0]) = pk.v;
    }
    bp0 += __shfl_xor(bp0, 1, 64); bp1 += __shfl_xor(bp1, 1, 64);
    bp2 += __shfl_xor(bp2, 1, 64); bp3 += __shfl_xor(bp3, 1, 64);
    if (!half) {
        int r = m0 + row;
        bterm[0 * NN + r] = bp0 * LOG2E; bterm[1 * NN + r] = bp1 * LOG2E;
        bterm[2 * NN + r] = bp2 * LOG2E; bterm[3 * NN + r] = bp3 * LOG2E;
    }
    // --- 4 projection GEMMs, A-tile reused ---
    int wave = t >> 6, lane = t & 63;
    int wr = (wave >> 1) * 64, wc = (wave & 1) * 64;
    int li = lane & 15, lk = (lane >> 4) * 8;
    int rbase = (lane >> 4) * 4;
    const float* Ws[4] = { wq, wk, wv, wg };
    for (int nt = 0; nt < 4; ++nt) {
        if (nt) __syncthreads();
        const float* wsrc = Ws[nt];
        #pragma unroll
        for (int it = 0; it < 16; ++it) {
            int k = it * 8 + (t >> 5);
            int n4 = (t & 31) * 4;
            float4 w = *(const float4*)(wsrc + k * 128 + n4);
            Bt[n4 + 0][k] = f2bf(w.x); Bt[n4 + 1][k] = f2bf(w.y);
            Bt[n4 + 2][k] = f2bf(w.z); Bt[n4 + 3][k] = f2bf(w.w);
        }
        __syncthreads();
        f32x4 acc[4][4] = {};
        #pragma unroll
        for (int kk = 0; kk < 4; ++kk) {
            bf16x8 af[4], bfr[4];
            #pragma unroll
            for (int i = 0; i < 4; ++i) af[i] = *(const bf16x8*)(&A[wr + i * 16 + li][kk * 32 + lk]);
            #pragma unroll
            for (int j = 0; j < 4; ++j) bfr[j] = *(const bf16x8*)(&Bt[wc + j * 16 + li][kk * 32 + lk]);
            __builtin_amdgcn_s_setprio(1);
            #pragma unroll
            for (int i = 0; i < 4; ++i)
                #pragma unroll
                for (int j = 0; j < 4; ++j)
                    acc[i][j] = __builtin_amdgcn_mfma_f32_16x16x32_bf16(af[i], bfr[j], acc[i][j], 0, 0, 0);
            __builtin_amdgcn_s_setprio(0);
        }
        bool isg = (nt == 3), isq = (nt == 0);
        #pragma unroll
        for (int i = 0; i < 4; ++i) {
            #pragma unroll
            for (int j = 0; j < 4; ++j) {
                int col = wc + j * 16 + li;
                int gcol = nt * 128 + col;
                #pragma unroll
                for (int r = 0; r < 4; ++r) {
                    int grow = m0 + wr + i * 16 + rbase + r;
                    float v = acc[i][j][r];
                    if (isg) { v += bg[col]; v = 1.0f / (1.0f + __expf(-v)); }
                    if (isq) v *= QSCALE;
                    qkvg[(size_t)grow * 512 + gcol] = f2bf(v);
                }
            }
        }
    }
}

// ---------------- Kernel 2: fused attention per (m,h), online softmax over 2 chunks ----------------
__global__ __launch_bounds__(256) void k_attn(
    const unsigned short* __restrict__ qkvg,
    const float* __restrict__ bterm,
    const float* __restrict__ mask,
    unsigned short* __restrict__ opre)
{
    __shared__ unsigned short Kl[320][40];     // K rows [j][dc]
    __shared__ unsigned short VT[32][NPAD];    // V transposed [dc][j]
    __shared__ unsigned short Pl[4][16][PPAD]; // per-wave P, one 160-chunk at a time
    __shared__ float mb[320];
    int bid = blockIdx.x;
    int m = bid >> 2, h = bid & 3;
    int t = threadIdx.x;
    size_t base = (size_t)m * NRES * 512;
    for (int j = t; j < NRES; j += 256) {
        const bf16x8* src = (const bf16x8*)(qkvg + base + (size_t)j * 512 + 128 + h * 32);
        bf16x8* dst = (bf16x8*)(&Kl[j][0]);
        dst[0] = src[0]; dst[1] = src[1]; dst[2] = src[2]; dst[3] = src[3];
    }
    {
        int dc = t & 31, jg = t >> 5;
        #pragma unroll 8
        for (int jj = 0; jj < 40; jj += 2) {
            int j = jg * 40 + jj;
            unsigned short v0 = qkvg[base + (size_t)j * 512 + 256 + h * 32 + dc];
            unsigned short v1 = qkvg[base + (size_t)(j + 1) * 512 + 256 + h * 32 + dc];
            *(unsigned int*)(&VT[dc][j]) = (unsigned int)v0 | ((unsigned int)v1 << 16);
        }
    }
    for (int j = t; j < NRES; j += 256) mb[j] = (100000.0f * LOG2E) * (mask[(size_t)m * NRES + j] - 1.0f);
    __syncthreads();

    int wave = t >> 6, lane = t & 63;
    int li = lane & 15, lg = lane >> 4;
    for (int c = 0; c < 5; ++c) {
        int i0 = wave * 80 + c * 16;
        int i = i0 + li;
        size_t qrow = base + (size_t)i * 512;
        bf16x8 qf = *(const bf16x8*)(qkvg + qrow + h * 32 + lg * 8);
        const float* brow = bterm + (size_t)h * NN + (size_t)i * NRES;
        f32x4 z = {0.f, 0.f, 0.f, 0.f};
        float mrun = -3.0e38f, sum = 0.0f;
        f32x4 o0 = {0.f, 0.f, 0.f, 0.f}, o1 = {0.f, 0.f, 0.f, 0.f};
        #pragma unroll
        for (int ph = 0; ph < 2; ++ph) {
            f32x4 st[10];
            __builtin_amdgcn_s_setprio(1);
            #pragma unroll
            for (int jf = 0; jf < 10; ++jf) {
                bf16x8 kf = *(const bf16x8*)(&Kl[ph * 160 + jf * 16 + li][lg * 8]);
                st[jf] = __builtin_amdgcn_mfma_f32_16x16x32_bf16(kf, qf, z, 0, 0, 0);
            }
            __builtin_amdgcn_s_setprio(0);
            float mx = mrun;
            #pragma unroll
            for (int jf = 0; jf < 10; ++jf) {
                int j0 = ph * 160 + jf * 16 + lg * 4;
                float4 bb = *(const float4*)(brow + j0);
                float4 mm = *(const float4*)(&mb[j0]);
                st[jf][0] += bb.x + mm.x;
                st[jf][1] += bb.y + mm.y;
                st[jf][2] += bb.z + mm.z;
                st[jf][3] += bb.w + mm.w;
                mx = fmaxf(mx, fmaxf(fmaxf(st[jf][0], st[jf][1]), fmaxf(st[jf][2], st[jf][3])));
            }
            mx = fmaxf(mx, __shfl_xor(mx, 16, 64));
            mx = fmaxf(mx, __shfl_xor(mx, 32, 64));
            if (ph) {  // compile-time after unroll: rescale previous chunk's state
                float corr = __builtin_amdgcn_exp2f(mrun - mx);
                sum *= corr;
                #pragma unroll
                for (int r = 0; r < 4; ++r) { o0[r] *= corr; o1[r] *= corr; }
            }
            mrun = mx;
            #pragma unroll
            for (int jf = 0; jf < 10; ++jf) {
                float p0 = __builtin_amdgcn_exp2f(st[jf][0] - mx);
                float p1 = __builtin_amdgcn_exp2f(st[jf][1] - mx);
                float p2 = __builtin_amdgcn_exp2f(st[jf][2] - mx);
                float p3 = __builtin_amdgcn_exp2f(st[jf][3] - mx);
                sum += (p0 + p1) + (p2 + p3);
                unsigned int lo = (unsigned int)f2bf(p0) | ((unsigned int)f2bf(p1) << 16);
                unsigned int hi = (unsigned int)f2bf(p2) | ((unsigned int)f2bf(p3) << 16);
                unsigned int* dst = (unsigned int*)(&Pl[wave][li][jf * 16 + lg * 4]);
                dst[0] = lo; dst[1] = hi;
            }
            __builtin_amdgcn_s_setprio(1);
            #pragma unroll
            for (int kk = 0; kk < 5; ++kk) {
                bf16x8 pf = *(const bf16x8*)(&Pl[wave][li][kk * 32 + lg * 8]);
                bf16x8 va = *(const bf16x8*)(&VT[li][ph * 160 + kk * 32 + lg * 8]);
                bf16x8 vb = *(const bf16x8*)(&VT[16 + li][ph * 160 + kk * 32 + lg * 8]);
                o0 = __builtin_amdgcn_mfma_f32_16x16x32_bf16(va, pf, o0, 0, 0, 0);
                o1 = __builtin_amdgcn_mfma_f32_16x16x32_bf16(vb, pf, o1, 0, 0, 0);
            }
            __builtin_amdgcn_s_setprio(0);
        }
        sum += __shfl_xor(sum, 16, 64);
        sum += __shfl_xor(sum, 32, 64);
        float inv = 1.0f / sum;
        size_t orow = ((size_t)m * NRES + i) * CCH + h * 32;
        #pragma unroll
        for (int df = 0; df < 2; ++df) {
            f32x4 o = df ? o1 : o0;
            int dcb = df * 16 + lg * 4;
            u16x4 gv = *(const u16x4*)(qkvg + qrow + 384 + h * 32 + dcb);
            u16x4 ov;
            #pragma unroll
            for (int r = 0; r < 4; ++r) ov[r] = f2bf(o[r] * inv * bf2f(gv[r]));
            *(u16x4*)(opre + orow + dcb) = ov;
        }
    }
}

// ---------------- Kernel 3: out = opre @ wo + bo (f32 out) ----------------
__global__ __launch_bounds__(256) void k_out(
    const unsigned short* __restrict__ opre, const float* __restrict__ wo,
    const float* __restrict__ bo, float* __restrict__ out)
{
    __shared__ unsigned short A[128][136];
    __shared__ unsigned short Bt[128][136];
    int m0 = blockIdx.x * 128;
    int t = threadIdx.x;
    #pragma unroll
    for (int it = 0; it < 8; ++it) {
        int idx = it * 256 + t;
        int row = idx >> 4, chunk = idx & 15;
        *(bf16x8*)(&A[row][chunk * 8]) = *(const bf16x8*)(opre + (size_t)(m0 + row) * CCH + chunk * 8);
    }
    #pragma unroll
    for (int it = 0; it < 16; ++it) {
        int k = it * 8 + (t >> 5);
        int n4 = (t & 31) * 4;
        float4 w = *(const float4*)(wo + k * 128 + n4);
        Bt[n4 + 0][k] = f2bf(w.x); Bt[n4 + 1][k] = f2bf(w.y);
        Bt[n4 + 2][k] = f2bf(w.z); Bt[n4 + 3][k] = f2bf(w.w);
    }
    __syncthreads();
    int wave = t >> 6, lane = t & 63;
    int wr = (wave >> 1) * 64, wc = (wave & 1) * 64;
    int li = lane & 15, lk = (lane >> 4) * 8;
    f32x4 acc[4][4] = {};
    #pragma unroll
    for (int kk = 0; kk < 4; ++kk) {
        bf16x8 af[4], bfr[4];
        #pragma unroll
        for (int i = 0; i < 4; ++i) af[i] = *(const bf16x8*)(&A[wr + i * 16 + li][kk * 32 + lk]);
        #pragma unroll
        for (int j = 0; j < 4; ++j) bfr[j] = *(const bf16x8*)(&Bt[wc + j * 16 + li][kk * 32 + lk]);
        __builtin_amdgcn_s_setprio(1);
        #pragma unroll
        for (int i = 0; i < 4; ++i)
            #pragma unroll
            for (int j = 0; j < 4; ++j)
                acc[i][j] = __builtin_amdgcn_mfma_f32_16x16x32_bf16(af[i], bfr[j], acc[i][j], 0, 0, 0);
        __builtin_amdgcn_s_setprio(0);
    }
    int rbase = (lane >> 4) * 4;
    #pragma unroll
    for (int i = 0; i < 4; ++i) {
        #pragma unroll
        for (int j = 0; j < 4; ++j) {
            int col = wc + j * 16 + li;
            #pragma unroll
            for (int r = 0; r < 4; ++r) {
                int grow = m0 + wr + i * 16 + rbase + r;
                out[(size_t)grow * CCH + col] = acc[i][j][r] + bo[col];
            }
        }
    }
}

extern "C" void kernel_launch(void* const* d_in, const int* in_sizes, int n_in,
                              void* d_out, int out_size, void* d_ws, size_t ws_size,
                              hipStream_t stream) {
    const float* x2d  = (const float*)d_in[0];
    const float* mask = (const float*)d_in[1];
    const float* ln_g = (const float*)d_in[2];
    const float* ln_b = (const float*)d_in[3];
    const float* wq   = (const float*)d_in[4];
    const float* wk   = (const float*)d_in[5];
    const float* wv   = (const float*)d_in[6];
    const float* wb   = (const float*)d_in[7];
    const float* wg   = (const float*)d_in[8];
    const float* bg   = (const float*)d_in[9];
    const float* wo   = (const float*)d_in[10];
    const float* bo   = (const float*)d_in[11];
    float* out = (float*)d_out;

    char* ws = (char*)d_ws;
    unsigned short* opre  = (unsigned short*)ws;                                 // 26,214,400 B
    unsigned short* qkvg  = (unsigned short*)(ws + 26214400);                    // 104,857,600 B
    float*          bterm = (float*)(ws + 26214400 + 104857600);                 // 1,638,400 B

    if (ws_size < (size_t)(26214400 + 104857600 + 1638400)) return;

    k_projln<<<800, 256, 0, stream>>>(x2d, ln_g, ln_b, wb, wq, wk, wv, wg, bg, qkvg, bterm);
    k_attn<<<1280, 256, 0, stream>>>(qkvg, bterm, mask, opre);
    k_out<<<800, 256, 0, stream>>>(opre, wo, bo, out);
}

// Round 6
// 291.362 us; speedup vs baseline: 1.5874x; 1.2870x over previous
//
#include <hip/hip_runtime.h>

typedef __attribute__((ext_vector_type(8))) short bf16x8;
typedef __attribute__((ext_vector_type(4))) float f32x4;
typedef __attribute__((ext_vector_type(4))) unsigned short u16x4;

#define DEVI static __device__ __forceinline__

DEVI float bf2f(unsigned short u) {
    union { unsigned int ui; float f; } c; c.ui = ((unsigned int)u) << 16; return c.f;
}
DEVI unsigned short f2bf(float f) {
    union { float f; unsigned int ui; } c; c.f = f;
    unsigned int u = c.ui;
    u += 0x7FFFu + ((u >> 16) & 1u);
    return (unsigned short)(u >> 16);
}

#define NRES 320
#define NN   102400
#define CCH  128
#define NPAD 344
#define PPAD 168

#define LOG2E 1.4426950408889634f
#define QSCALE (0.17677669529663687f * 1.4426950408889634f)

// ---------------- Kernel 1: LayerNorm -> xn(bf16) + bterm (log2e-scaled) ----------------
__global__ __launch_bounds__(256) void k_ln_bias(
    const float* __restrict__ x2d, const float* __restrict__ ln_g,
    const float* __restrict__ ln_b, const float* __restrict__ wb,
    unsigned short* __restrict__ xn, float* __restrict__ bterm)
{
    int wave = threadIdx.x >> 6, lane = threadIdx.x & 63;
    int r = blockIdx.x * 4 + wave;
    int c0 = lane * 2;
    float2 x = *(const float2*)(x2d + (size_t)r * CCH + c0);
    float s = x.x + x.y, sq = x.x * x.x + x.y * x.y;
    #pragma unroll
    for (int m = 1; m < 64; m <<= 1) { s += __shfl_xor(s, m, 64); sq += __shfl_xor(sq, m, 64); }
    float mu = s * (1.0f / 128.0f);
    float var = sq * (1.0f / 128.0f) - mu * mu;
    float rstd = rsqrtf(var + 1e-5f);
    float xn0 = (x.x - mu) * rstd * ln_g[c0] + ln_b[c0];
    float xn1 = (x.y - mu) * rstd * ln_g[c0 + 1] + ln_b[c0 + 1];
    unsigned int packed = (unsigned int)f2bf(xn0) | ((unsigned int)f2bf(xn1) << 16);
    *(unsigned int*)(xn + (size_t)r * CCH + c0) = packed;
    float4 w0 = *(const float4*)(wb + c0 * 4);
    float4 w1 = *(const float4*)(wb + c0 * 4 + 4);
    float b0 = xn0 * w0.x + xn1 * w1.x;
    float b1 = xn0 * w0.y + xn1 * w1.y;
    float b2 = xn0 * w0.z + xn1 * w1.z;
    float b3 = xn0 * w0.w + xn1 * w1.w;
    #pragma unroll
    for (int m = 1; m < 64; m <<= 1) {
        b0 += __shfl_xor(b0, m, 64); b1 += __shfl_xor(b1, m, 64);
        b2 += __shfl_xor(b2, m, 64); b3 += __shfl_xor(b3, m, 64);
    }
    if (lane == 0) {
        bterm[0 * NN + r] = b0 * LOG2E; bterm[1 * NN + r] = b1 * LOG2E;
        bterm[2 * NN + r] = b2 * LOG2E; bterm[3 * NN + r] = b3 * LOG2E;
    }
}

// ---------------- Kernel 2: qkvg = xn @ W[nt] (grid.y = nt; conflict-free B staging) ----------------
__global__ __launch_bounds__(256) void k_proj(
    const unsigned short* __restrict__ xn,
    const float* __restrict__ wq, const float* __restrict__ wk,
    const float* __restrict__ wv, const float* __restrict__ wg,
    const float* __restrict__ bg,
    unsigned short* __restrict__ qkvg)
{
    __shared__ unsigned short A[128][136];
    __shared__ unsigned short Bt[128][136];   // Bt[n][k]
    int m0 = blockIdx.x * 128;
    int nt = blockIdx.y;
    int t = threadIdx.x;
    const float* wsrc = (nt == 0) ? wq : (nt == 1) ? wk : (nt == 2) ? wv : wg;
    // A stage: coalesced bf16x8, conflict-free
    #pragma unroll
    for (int it = 0; it < 8; ++it) {
        int idx = it * 256 + t;
        int row = idx >> 4, chunk = idx & 15;
        *(bf16x8*)(&A[row][chunk * 8]) = *(const bf16x8*)(xn + (size_t)(m0 + row) * CCH + chunk * 8);
    }
    // B stage: thread owns column n (lane-stride-1), scalar loads along k, b128 writes
    {
        int n = t & 127, p = t >> 7;
        const float* col = wsrc + n;
        #pragma unroll
        for (int q = 0; q < 8; ++q) {
            int k0 = p * 64 + q * 8;
            union { unsigned short u[8]; bf16x8 v; } pk;
            #pragma unroll
            for (int z = 0; z < 8; ++z) pk.u[z] = f2bf(col[(size_t)(k0 + z) * 128]);
            *(bf16x8*)(&Bt[n][k0]) = pk.v;
        }
    }
    __syncthreads();
    int wave = t >> 6, lane = t & 63;
    int wr = (wave >> 1) * 64, wc = (wave & 1) * 64;
    int li = lane & 15, lk = (lane >> 4) * 8;
    f32x4 acc[4][4] = {};
    #pragma unroll
    for (int kk = 0; kk < 4; ++kk) {
        bf16x8 af[4], bfr[4];
        #pragma unroll
        for (int i = 0; i < 4; ++i) af[i] = *(const bf16x8*)(&A[wr + i * 16 + li][kk * 32 + lk]);
        #pragma unroll
        for (int j = 0; j < 4; ++j) bfr[j] = *(const bf16x8*)(&Bt[wc + j * 16 + li][kk * 32 + lk]);
        __builtin_amdgcn_s_setprio(1);
        #pragma unroll
        for (int i = 0; i < 4; ++i)
            #pragma unroll
            for (int j = 0; j < 4; ++j)
                acc[i][j] = __builtin_amdgcn_mfma_f32_16x16x32_bf16(af[i], bfr[j], acc[i][j], 0, 0, 0);
        __builtin_amdgcn_s_setprio(0);
    }
    int rbase = (lane >> 4) * 4;
    bool isg = (nt == 3), isq = (nt == 0);
    #pragma unroll
    for (int i = 0; i < 4; ++i) {
        #pragma unroll
        for (int j = 0; j < 4; ++j) {
            int col = wc + j * 16 + li;
            int gcol = nt * 128 + col;
            #pragma unroll
            for (int r = 0; r < 4; ++r) {
                int grow = m0 + wr + i * 16 + rbase + r;
                float v = acc[i][j][r];
                if (isg) { v += bg[col]; v = 1.0f / (1.0f + __expf(-v)); }
                if (isq) v *= QSCALE;
                qkvg[(size_t)grow * 512 + gcol] = f2bf(v);
            }
        }
    }
}

// ---------------- Kernel 3: fused attention per (m,h), online softmax over 2 chunks ----------------
__global__ __launch_bounds__(256) void k_attn(
    const unsigned short* __restrict__ qkvg,
    const float* __restrict__ bterm,
    const float* __restrict__ mask,
    unsigned short* __restrict__ opre)
{
    __shared__ unsigned short Kl[320][40];     // K rows [j][dc]
    __shared__ unsigned short VT[32][NPAD];    // V transposed [dc][j]
    __shared__ unsigned short Pl[4][16][PPAD]; // per-wave P, one 160-chunk at a time
    __shared__ float mb[320];
    int bid = blockIdx.x;
    int m = bid >> 2, h = bid & 3;
    int t = threadIdx.x;
    size_t base = (size_t)m * NRES * 512;
    for (int j = t; j < NRES; j += 256) {
        const bf16x8* src = (const bf16x8*)(qkvg + base + (size_t)j * 512 + 128 + h * 32);
        bf16x8* dst = (bf16x8*)(&Kl[j][0]);
        dst[0] = src[0]; dst[1] = src[1]; dst[2] = src[2]; dst[3] = src[3];
    }
    {
        int dc = t & 31, jg = t >> 5;
        #pragma unroll 8
        for (int jj = 0; jj < 40; jj += 2) {
            int j = jg * 40 + jj;
            unsigned short v0 = qkvg[base + (size_t)j * 512 + 256 + h * 32 + dc];
            unsigned short v1 = qkvg[base + (size_t)(j + 1) * 512 + 256 + h * 32 + dc];
            *(unsigned int*)(&VT[dc][j]) = (unsigned int)v0 | ((unsigned int)v1 << 16);
        }
    }
    for (int j = t; j < NRES; j += 256) mb[j] = (100000.0f * LOG2E) * (mask[(size_t)m * NRES + j] - 1.0f);
    __syncthreads();

    int wave = t >> 6, lane = t & 63;
    int li = lane & 15, lg = lane >> 4;
    for (int c = 0; c < 5; ++c) {
        int i0 = wave * 80 + c * 16;
        int i = i0 + li;
        size_t qrow = base + (size_t)i * 512;
        bf16x8 qf = *(const bf16x8*)(qkvg + qrow + h * 32 + lg * 8);
        const float* brow = bterm + (size_t)h * NN + (size_t)i * NRES;
        f32x4 z = {0.f, 0.f, 0.f, 0.f};
        float mrun = -3.0e38f, sum = 0.0f;
        f32x4 o0 = {0.f, 0.f, 0.f, 0.f}, o1 = {0.f, 0.f, 0.f, 0.f};
        #pragma unroll
        for (int ph = 0; ph < 2; ++ph) {
            f32x4 st[10];
            __builtin_amdgcn_s_setprio(1);
            #pragma unroll
            for (int jf = 0; jf < 10; ++jf) {
                bf16x8 kf = *(const bf16x8*)(&Kl[ph * 160 + jf * 16 + li][lg * 8]);
                st[jf] = __builtin_amdgcn_mfma_f32_16x16x32_bf16(kf, qf, z, 0, 0, 0);
            }
            __builtin_amdgcn_s_setprio(0);
            float mx = mrun;
            #pragma unroll
            for (int jf = 0; jf < 10; ++jf) {
                int j0 = ph * 160 + jf * 16 + lg * 4;
                float4 bb = *(const float4*)(brow + j0);
                float4 mm = *(const float4*)(&mb[j0]);
                st[jf][0] += bb.x + mm.x;
                st[jf][1] += bb.y + mm.y;
                st[jf][2] += bb.z + mm.z;
                st[jf][3] += bb.w + mm.w;
                mx = fmaxf(mx, fmaxf(fmaxf(st[jf][0], st[jf][1]), fmaxf(st[jf][2], st[jf][3])));
            }
            mx = fmaxf(mx, __shfl_xor(mx, 16, 64));
            mx = fmaxf(mx, __shfl_xor(mx, 32, 64));
            if (ph) {
                float corr = __builtin_amdgcn_exp2f(mrun - mx);
                sum *= corr;
                #pragma unroll
                for (int r = 0; r < 4; ++r) { o0[r] *= corr; o1[r] *= corr; }
            }
            mrun = mx;
            #pragma unroll
            for (int jf = 0; jf < 10; ++jf) {
                float p0 = __builtin_amdgcn_exp2f(st[jf][0] - mx);
                float p1 = __builtin_amdgcn_exp2f(st[jf][1] - mx);
                float p2 = __builtin_amdgcn_exp2f(st[jf][2] - mx);
                float p3 = __builtin_amdgcn_exp2f(st[jf][3] - mx);
                sum += (p0 + p1) + (p2 + p3);
                unsigned int lo = (unsigned int)f2bf(p0) | ((unsigned int)f2bf(p1) << 16);
                unsigned int hi = (unsigned int)f2bf(p2) | ((unsigned int)f2bf(p3) << 16);
                unsigned int* dst = (unsigned int*)(&Pl[wave][li][jf * 16 + lg * 4]);
                dst[0] = lo; dst[1] = hi;
            }
            __builtin_amdgcn_s_setprio(1);
            #pragma unroll
            for (int kk = 0; kk < 5; ++kk) {
                bf16x8 pf = *(const bf16x8*)(&Pl[wave][li][kk * 32 + lg * 8]);
                bf16x8 va = *(const bf16x8*)(&VT[li][ph * 160 + kk * 32 + lg * 8]);
                bf16x8 vb = *(const bf16x8*)(&VT[16 + li][ph * 160 + kk * 32 + lg * 8]);
                o0 = __builtin_amdgcn_mfma_f32_16x16x32_bf16(va, pf, o0, 0, 0, 0);
                o1 = __builtin_amdgcn_mfma_f32_16x16x32_bf16(vb, pf, o1, 0, 0, 0);
            }
            __builtin_amdgcn_s_setprio(0);
        }
        sum += __shfl_xor(sum, 16, 64);
        sum += __shfl_xor(sum, 32, 64);
        float inv = 1.0f / sum;
        size_t orow = ((size_t)m * NRES + i) * CCH + h * 32;
        #pragma unroll
        for (int df = 0; df < 2; ++df) {
            f32x4 o = df ? o1 : o0;
            int dcb = df * 16 + lg * 4;
            u16x4 gv = *(const u16x4*)(qkvg + qrow + 384 + h * 32 + dcb);
            u16x4 ov;
            #pragma unroll
            for (int r = 0; r < 4; ++r) ov[r] = f2bf(o[r] * inv * bf2f(gv[r]));
            *(u16x4*)(opre + orow + dcb) = ov;
        }
    }
}

// ---------------- Kernel 4: out = opre @ wo + bo (f32 out; conflict-free B staging) ----------------
__global__ __launch_bounds__(256) void k_out(
    const unsigned short* __restrict__ opre, const float* __restrict__ wo,
    const float* __restrict__ bo, float* __restrict__ out)
{
    __shared__ unsigned short A[128][136];
    __shared__ unsigned short Bt[128][136];
    int m0 = blockIdx.x * 128;
    int t = threadIdx.x;
    #pragma unroll
    for (int it = 0; it < 8; ++it) {
        int idx = it * 256 + t;
        int row = idx >> 4, chunk = idx & 15;
        *(bf16x8*)(&A[row][chunk * 8]) = *(const bf16x8*)(opre + (size_t)(m0 + row) * CCH + chunk * 8);
    }
    {
        int n = t & 127, p = t >> 7;
        const float* col = wo + n;
        #pragma unroll
        for (int q = 0; q < 8; ++q) {
            int k0 = p * 64 + q * 8;
            union { unsigned short u[8]; bf16x8 v; } pk;
            #pragma unroll
            for (int z = 0; z < 8; ++z) pk.u[z] = f2bf(col[(size_t)(k0 + z) * 128]);
            *(bf16x8*)(&Bt[n][k0]) = pk.v;
        }
    }
    __syncthreads();
    int wave = t >> 6, lane = t & 63;
    int wr = (wave >> 1) * 64, wc = (wave & 1) * 64;
    int li = lane & 15, lk = (lane >> 4) * 8;
    f32x4 acc[4][4] = {};
    #pragma unroll
    for (int kk = 0; kk < 4; ++kk) {
        bf16x8 af[4], bfr[4];
        #pragma unroll
        for (int i = 0; i < 4; ++i) af[i] = *(const bf16x8*)(&A[wr + i * 16 + li][kk * 32 + lk]);
        #pragma unroll
        for (int j = 0; j < 4; ++j) bfr[j] = *(const bf16x8*)(&Bt[wc + j * 16 + li][kk * 32 + lk]);
        __builtin_amdgcn_s_setprio(1);
        #pragma unroll
        for (int i = 0; i < 4; ++i)
            #pragma unroll
            for (int j = 0; j < 4; ++j)
                acc[i][j] = __builtin_amdgcn_mfma_f32_16x16x32_bf16(af[i], bfr[j], acc[i][j], 0, 0, 0);
        __builtin_amdgcn_s_setprio(0);
    }
    int rbase = (lane >> 4) * 4;
    #pragma unroll
    for (int i = 0; i < 4; ++i) {
        #pragma unroll
        for (int j = 0; j < 4; ++j) {
            int col = wc + j * 16 + li;
            #pragma unroll
            for (int r = 0; r < 4; ++r) {
                int grow = m0 + wr + i * 16 + rbase + r;
                out[(size_t)grow * CCH + col] = acc[i][j][r] + bo[col];
            }
        }
    }
}

extern "C" void kernel_launch(void* const* d_in, const int* in_sizes, int n_in,
                              void* d_out, int out_size, void* d_ws, size_t ws_size,
                              hipStream_t stream) {
    const float* x2d  = (const float*)d_in[0];
    const float* mask = (const float*)d_in[1];
    const float* ln_g = (const float*)d_in[2];
    const float* ln_b = (const float*)d_in[3];
    const float* wq   = (const float*)d_in[4];
    const float* wk   = (const float*)d_in[5];
    const float* wv   = (const float*)d_in[6];
    const float* wb   = (const float*)d_in[7];
    const float* wg   = (const float*)d_in[8];
    const float* bg   = (const float*)d_in[9];
    const float* wo   = (const float*)d_in[10];
    const float* bo   = (const float*)d_in[11];
    float* out = (float*)d_out;

    char* ws = (char*)d_ws;
    unsigned short* xn    = (unsigned short*)ws;                                 // 26,214,400 B (reused as opre)
    unsigned short* qkvg  = (unsigned short*)(ws + 26214400);                    // 104,857,600 B
    float*          bterm = (float*)(ws + 26214400 + 104857600);                 // 1,638,400 B
    unsigned short* opre  = xn;

    if (ws_size < (size_t)(26214400 + 104857600 + 1638400)) return;

    k_ln_bias<<<25600, 256, 0, stream>>>(x2d, ln_g, ln_b, wb, xn, bterm);
    k_proj<<<dim3(800, 4), 256, 0, stream>>>(xn, wq, wk, wv, wg, bg, qkvg);
    k_attn<<<1280, 256, 0, stream>>>(qkvg, bterm, mask, opre);
    k_out<<<800, 256, 0, stream>>>(opre, wo, bo, out);
}

// Round 7
// 229.782 us; speedup vs baseline: 2.0129x; 1.2680x over previous
//
#include <hip/hip_runtime.h>

typedef __attribute__((ext_vector_type(8))) short bf16x8;
typedef __attribute__((ext_vector_type(4))) float f32x4;
typedef __attribute__((ext_vector_type(4))) unsigned short u16x4;

#define DEVI static __device__ __forceinline__

DEVI float bf2f(unsigned short u) {
    union { unsigned int ui; float f; } c; c.ui = ((unsigned int)u) << 16; return c.f;
}
DEVI unsigned short f2bf(float f) {
    union { float f; unsigned int ui; } c; c.f = f;
    unsigned int u = c.ui;
    u += 0x7FFFu + ((u >> 16) & 1u);
    return (unsigned short)(u >> 16);
}

#define NRES 320
#define NN   102400
#define CCH  128
#define NPAD 344
#define PPAD 72    // 64-col phase + 8 pad

#define LOG2E 1.4426950408889634f
#define QSCALE (0.17677669529663687f * 1.4426950408889634f)

// ---------------- Kernel 1: LayerNorm -> xn(bf16) + bterm (log2e-scaled) ----------------
__global__ __launch_bounds__(256) void k_ln_bias(
    const float* __restrict__ x2d, const float* __restrict__ ln_g,
    const float* __restrict__ ln_b, const float* __restrict__ wb,
    unsigned short* __restrict__ xn, float* __restrict__ bterm)
{
    int wave = threadIdx.x >> 6, lane = threadIdx.x & 63;
    int r = blockIdx.x * 4 + wave;
    int c0 = lane * 2;
    float2 x = *(const float2*)(x2d + (size_t)r * CCH + c0);
    float s = x.x + x.y, sq = x.x * x.x + x.y * x.y;
    #pragma unroll
    for (int m = 1; m < 64; m <<= 1) { s += __shfl_xor(s, m, 64); sq += __shfl_xor(sq, m, 64); }
    float mu = s * (1.0f / 128.0f);
    float var = sq * (1.0f / 128.0f) - mu * mu;
    float rstd = rsqrtf(var + 1e-5f);
    float xn0 = (x.x - mu) * rstd * ln_g[c0] + ln_b[c0];
    float xn1 = (x.y - mu) * rstd * ln_g[c0 + 1] + ln_b[c0 + 1];
    unsigned int packed = (unsigned int)f2bf(xn0) | ((unsigned int)f2bf(xn1) << 16);
    *(unsigned int*)(xn + (size_t)r * CCH + c0) = packed;
    float4 w0 = *(const float4*)(wb + c0 * 4);
    float4 w1 = *(const float4*)(wb + c0 * 4 + 4);
    float b0 = xn0 * w0.x + xn1 * w1.x;
    float b1 = xn0 * w0.y + xn1 * w1.y;
    float b2 = xn0 * w0.z + xn1 * w1.z;
    float b3 = xn0 * w0.w + xn1 * w1.w;
    #pragma unroll
    for (int m = 1; m < 64; m <<= 1) {
        b0 += __shfl_xor(b0, m, 64); b1 += __shfl_xor(b1, m, 64);
        b2 += __shfl_xor(b2, m, 64); b3 += __shfl_xor(b3, m, 64);
    }
    if (lane == 0) {
        bterm[0 * NN + r] = b0 * LOG2E; bterm[1 * NN + r] = b1 * LOG2E;
        bterm[2 * NN + r] = b2 * LOG2E; bterm[3 * NN + r] = b3 * LOG2E;
    }
}

// ---------------- Kernel 2: qkvg = xn @ W[nt] (grid.y = nt; conflict-free B staging) ----------------
__global__ __launch_bounds__(256) void k_proj(
    const unsigned short* __restrict__ xn,
    const float* __restrict__ wq, const float* __restrict__ wk,
    const float* __restrict__ wv, const float* __restrict__ wg,
    const float* __restrict__ bg,
    unsigned short* __restrict__ qkvg)
{
    __shared__ unsigned short A[128][136];
    __shared__ unsigned short Bt[128][136];   // Bt[n][k]
    int m0 = blockIdx.x * 128;
    int nt = blockIdx.y;
    int t = threadIdx.x;
    const float* wsrc = (nt == 0) ? wq : (nt == 1) ? wk : (nt == 2) ? wv : wg;
    #pragma unroll
    for (int it = 0; it < 8; ++it) {
        int idx = it * 256 + t;
        int row = idx >> 4, chunk = idx & 15;
        *(bf16x8*)(&A[row][chunk * 8]) = *(const bf16x8*)(xn + (size_t)(m0 + row) * CCH + chunk * 8);
    }
    {
        int n = t & 127, p = t >> 7;
        const float* col = wsrc + n;
        #pragma unroll
        for (int q = 0; q < 8; ++q) {
            int k0 = p * 64 + q * 8;
            union { unsigned short u[8]; bf16x8 v; } pk;
            #pragma unroll
            for (int z = 0; z < 8; ++z) pk.u[z] = f2bf(col[(size_t)(k0 + z) * 128]);
            *(bf16x8*)(&Bt[n][k0]) = pk.v;
        }
    }
    __syncthreads();
    int wave = t >> 6, lane = t & 63;
    int wr = (wave >> 1) * 64, wc = (wave & 1) * 64;
    int li = lane & 15, lk = (lane >> 4) * 8;
    f32x4 acc[4][4] = {};
    #pragma unroll
    for (int kk = 0; kk < 4; ++kk) {
        bf16x8 af[4], bfr[4];
        #pragma unroll
        for (int i = 0; i < 4; ++i) af[i] = *(const bf16x8*)(&A[wr + i * 16 + li][kk * 32 + lk]);
        #pragma unroll
        for (int j = 0; j < 4; ++j) bfr[j] = *(const bf16x8*)(&Bt[wc + j * 16 + li][kk * 32 + lk]);
        __builtin_amdgcn_s_setprio(1);
        #pragma unroll
        for (int i = 0; i < 4; ++i)
            #pragma unroll
            for (int j = 0; j < 4; ++j)
                acc[i][j] = __builtin_amdgcn_mfma_f32_16x16x32_bf16(af[i], bfr[j], acc[i][j], 0, 0, 0);
        __builtin_amdgcn_s_setprio(0);
    }
    int rbase = (lane >> 4) * 4;
    bool isg = (nt == 3), isq = (nt == 0);
    #pragma unroll
    for (int i = 0; i < 4; ++i) {
        #pragma unroll
        for (int j = 0; j < 4; ++j) {
            int col = wc + j * 16 + li;
            int gcol = nt * 128 + col;
            #pragma unroll
            for (int r = 0; r < 4; ++r) {
                int grow = m0 + wr + i * 16 + rbase + r;
                float v = acc[i][j][r];
                if (isg) { v += bg[col]; v = 1.0f / (1.0f + __expf(-v)); }
                if (isq) v *= QSCALE;
                qkvg[(size_t)grow * 512 + gcol] = f2bf(v);
            }
        }
    }
}

// ---------------- Kernel 3: fused attention per (m,h), online softmax over 5×64 chunks ----------------
__global__ __launch_bounds__(256) void k_attn(
    const unsigned short* __restrict__ qkvg,
    const float* __restrict__ bterm,
    const float* __restrict__ mask,
    unsigned short* __restrict__ opre)
{
    __shared__ unsigned short Kl[320][40];     // K rows [j][dc]
    __shared__ unsigned short VT[32][NPAD];    // V transposed [dc][j]
    __shared__ unsigned short Pl[4][16][PPAD]; // per-wave P, one 64-chunk at a time
    __shared__ float mb[320];
    int bid = blockIdx.x;
    int m = bid >> 2, h = bid & 3;
    int t = threadIdx.x;
    size_t base = (size_t)m * NRES * 512;
    for (int j = t; j < NRES; j += 256) {
        const bf16x8* src = (const bf16x8*)(qkvg + base + (size_t)j * 512 + 128 + h * 32);
        bf16x8* dst = (bf16x8*)(&Kl[j][0]);
        dst[0] = src[0]; dst[1] = src[1]; dst[2] = src[2]; dst[3] = src[3];
    }
    {
        int dc = t & 31, jg = t >> 5;
        #pragma unroll 8
        for (int jj = 0; jj < 40; jj += 2) {
            int j = jg * 40 + jj;
            unsigned short v0 = qkvg[base + (size_t)j * 512 + 256 + h * 32 + dc];
            unsigned short v1 = qkvg[base + (size_t)(j + 1) * 512 + 256 + h * 32 + dc];
            *(unsigned int*)(&VT[dc][j]) = (unsigned int)v0 | ((unsigned int)v1 << 16);
        }
    }
    for (int j = t; j < NRES; j += 256) mb[j] = (100000.0f * LOG2E) * (mask[(size_t)m * NRES + j] - 1.0f);
    __syncthreads();

    int wave = t >> 6, lane = t & 63;
    int li = lane & 15, lg = lane >> 4;
    for (int c = 0; c < 5; ++c) {
        int i0 = wave * 80 + c * 16;
        int i = i0 + li;
        size_t qrow = base + (size_t)i * 512;
        bf16x8 qf = *(const bf16x8*)(qkvg + qrow + h * 32 + lg * 8);
        const float* brow = bterm + (size_t)h * NN + (size_t)i * NRES;
        f32x4 z = {0.f, 0.f, 0.f, 0.f};
        float mrun = -3.0e38f, sum = 0.0f;
        f32x4 o0 = {0.f, 0.f, 0.f, 0.f}, o1 = {0.f, 0.f, 0.f, 0.f};
        #pragma unroll 1
        for (int ph = 0; ph < 5; ++ph) {
            f32x4 st[4];
            __builtin_amdgcn_s_setprio(1);
            #pragma unroll
            for (int jf = 0; jf < 4; ++jf) {
                bf16x8 kf = *(const bf16x8*)(&Kl[ph * 64 + jf * 16 + li][lg * 8]);
                st[jf] = __builtin_amdgcn_mfma_f32_16x16x32_bf16(kf, qf, z, 0, 0, 0);
            }
            __builtin_amdgcn_s_setprio(0);
            float mx = mrun;
            #pragma unroll
            for (int jf = 0; jf < 4; ++jf) {
                int j0 = ph * 64 + jf * 16 + lg * 4;
                float4 bb = *(const float4*)(brow + j0);
                float4 mm = *(const float4*)(&mb[j0]);
                st[jf][0] += bb.x + mm.x;
                st[jf][1] += bb.y + mm.y;
                st[jf][2] += bb.z + mm.z;
                st[jf][3] += bb.w + mm.w;
                mx = fmaxf(mx, fmaxf(fmaxf(st[jf][0], st[jf][1]), fmaxf(st[jf][2], st[jf][3])));
            }
            mx = fmaxf(mx, __shfl_xor(mx, 16, 64));
            mx = fmaxf(mx, __shfl_xor(mx, 32, 64));
            if (ph) {
                float corr = __builtin_amdgcn_exp2f(mrun - mx);
                sum *= corr;
                #pragma unroll
                for (int r = 0; r < 4; ++r) { o0[r] *= corr; o1[r] *= corr; }
            }
            mrun = mx;
            #pragma unroll
            for (int jf = 0; jf < 4; ++jf) {
                float p0 = __builtin_amdgcn_exp2f(st[jf][0] - mx);
                float p1 = __builtin_amdgcn_exp2f(st[jf][1] - mx);
                float p2 = __builtin_amdgcn_exp2f(st[jf][2] - mx);
                float p3 = __builtin_amdgcn_exp2f(st[jf][3] - mx);
                sum += (p0 + p1) + (p2 + p3);
                unsigned int lo = (unsigned int)f2bf(p0) | ((unsigned int)f2bf(p1) << 16);
                unsigned int hi = (unsigned int)f2bf(p2) | ((unsigned int)f2bf(p3) << 16);
                unsigned int* dst = (unsigned int*)(&Pl[wave][li][jf * 16 + lg * 4]);
                dst[0] = lo; dst[1] = hi;
            }
            __builtin_amdgcn_s_setprio(1);
            #pragma unroll
            for (int kk = 0; kk < 2; ++kk) {
                bf16x8 pf = *(const bf16x8*)(&Pl[wave][li][kk * 32 + lg * 8]);
                bf16x8 va = *(const bf16x8*)(&VT[li][ph * 64 + kk * 32 + lg * 8]);
                bf16x8 vb = *(const bf16x8*)(&VT[16 + li][ph * 64 + kk * 32 + lg * 8]);
                o0 = __builtin_amdgcn_mfma_f32_16x16x32_bf16(va, pf, o0, 0, 0, 0);
                o1 = __builtin_amdgcn_mfma_f32_16x16x32_bf16(vb, pf, o1, 0, 0, 0);
            }
            __builtin_amdgcn_s_setprio(0);
        }
        sum += __shfl_xor(sum, 16, 64);
        sum += __shfl_xor(sum, 32, 64);
        float inv = 1.0f / sum;
        size_t orow = ((size_t)m * NRES + i) * CCH + h * 32;
        #pragma unroll
        for (int df = 0; df < 2; ++df) {
            f32x4 o = df ? o1 : o0;
            int dcb = df * 16 + lg * 4;
            u16x4 gv = *(const u16x4*)(qkvg + qrow + 384 + h * 32 + dcb);
            u16x4 ov;
            #pragma unroll
            for (int r = 0; r < 4; ++r) ov[r] = f2bf(o[r] * inv * bf2f(gv[r]));
            *(u16x4*)(opre + orow + dcb) = ov;
        }
    }
}

// ---------------- Kernel 4: out = opre @ wo + bo (f32 out; conflict-free B staging) ----------------
__global__ __launch_bounds__(256) void k_out(
    const unsigned short* __restrict__ opre, const float* __restrict__ wo,
    const float* __restrict__ bo, float* __restrict__ out)
{
    __shared__ unsigned short A[128][136];
    __shared__ unsigned short Bt[128][136];
    int m0 = blockIdx.x * 128;
    int t = threadIdx.x;
    #pragma unroll
    for (int it = 0; it < 8; ++it) {
        int idx = it * 256 + t;
        int row = idx >> 4, chunk = idx & 15;
        *(bf16x8*)(&A[row][chunk * 8]) = *(const bf16x8*)(opre + (size_t)(m0 + row) * CCH + chunk * 8);
    }
    {
        int n = t & 127, p = t >> 7;
        const float* col = wo + n;
        #pragma unroll
        for (int q = 0; q < 8; ++q) {
            int k0 = p * 64 + q * 8;
            union { unsigned short u[8]; bf16x8 v; } pk;
            #pragma unroll
            for (int z = 0; z < 8; ++z) pk.u[z] = f2bf(col[(size_t)(k0 + z) * 128]);
            *(bf16x8*)(&Bt[n][k0]) = pk.v;
        }
    }
    __syncthreads();
    int wave = t >> 6, lane = t & 63;
    int wr = (wave >> 1) * 64, wc = (wave & 1) * 64;
    int li = lane & 15, lk = (lane >> 4) * 8;
    f32x4 acc[4][4] = {};
    #pragma unroll
    for (int kk = 0; kk < 4; ++kk) {
        bf16x8 af[4], bfr[4];
        #pragma unroll
        for (int i = 0; i < 4; ++i) af[i] = *(const bf16x8*)(&A[wr + i * 16 + li][kk * 32 + lk]);
        #pragma unroll
        for (int j = 0; j < 4; ++j) bfr[j] = *(const bf16x8*)(&Bt[wc + j * 16 + li][kk * 32 + lk]);
        __builtin_amdgcn_s_setprio(1);
        #pragma unroll
        for (int i = 0; i < 4; ++i)
            #pragma unroll
            for (int j = 0; j < 4; ++j)
                acc[i][j] = __builtin_amdgcn_mfma_f32_16x16x32_bf16(af[i], bfr[j], acc[i][j], 0, 0, 0);
        __builtin_amdgcn_s_setprio(0);
    }
    int rbase = (lane >> 4) * 4;
    #pragma unroll
    for (int i = 0; i < 4; ++i) {
        #pragma unroll
        for (int j = 0; j < 4; ++j) {
            int col = wc + j * 16 + li;
            #pragma unroll
            for (int r = 0; r < 4; ++r) {
                int grow = m0 + wr + i * 16 + rbase + r;
                out[(size_t)grow * CCH + col] = acc[i][j][r] + bo[col];
            }
        }
    }
}

extern "C" void kernel_launch(void* const* d_in, const int* in_sizes, int n_in,
                              void* d_out, int out_size, void* d_ws, size_t ws_size,
                              hipStream_t stream) {
    const float* x2d  = (const float*)d_in[0];
    const float* mask = (const float*)d_in[1];
    const float* ln_g = (const float*)d_in[2];
    const float* ln_b = (const float*)d_in[3];
    const float* wq   = (const float*)d_in[4];
    const float* wk   = (const float*)d_in[5];
    const float* wv   = (const float*)d_in[6];
    const float* wb   = (const float*)d_in[7];
    const float* wg   = (const float*)d_in[8];
    const float* bg   = (const float*)d_in[9];
    const float* wo   = (const float*)d_in[10];
    const float* bo   = (const float*)d_in[11];
    float* out = (float*)d_out;

    char* ws = (char*)d_ws;
    unsigned short* xn    = (unsigned short*)ws;                                 // 26,214,400 B (reused as opre)
    unsigned short* qkvg  = (unsigned short*)(ws + 26214400);                    // 104,857,600 B
    float*          bterm = (float*)(ws + 26214400 + 104857600);                 // 1,638,400 B
    unsigned short* opre  = xn;

    if (ws_size < (size_t)(26214400 + 104857600 + 1638400)) return;

    k_ln_bias<<<25600, 256, 0, stream>>>(x2d, ln_g, ln_b, wb, xn, bterm);
    k_proj<<<dim3(800, 4), 256, 0, stream>>>(xn, wq, wk, wv, wg, bg, qkvg);
    k_attn<<<1280, 256, 0, stream>>>(qkvg, bterm, mask, opre);
    k_out<<<800, 256, 0, stream>>>(opre, wo, bo, out);
}

// Round 8
// 213.586 us; speedup vs baseline: 2.1655x; 1.0758x over previous
//
#include <hip/hip_runtime.h>
#include <hip/hip_bf16.h>

typedef __attribute__((ext_vector_type(8))) short bf16x8;
typedef __attribute__((ext_vector_type(4))) float f32x4;
typedef __attribute__((ext_vector_type(4))) unsigned short u16x4;

#define DEVI static __device__ __forceinline__

DEVI float bf2f(unsigned short u) {
    union { unsigned int ui; float f; } c; c.ui = ((unsigned int)u) << 16; return c.f;
}
DEVI unsigned short f2bf(float f) {
    union { float f; unsigned int ui; } c; c.f = f;
    unsigned int u = c.ui;
    u += 0x7FFFu + ((u >> 16) & 1u);
    return (unsigned short)(u >> 16);
}
DEVI unsigned int pk2bf(float a, float b) {   // v_cvt_pk_bf16_f32 via compiler
    union { __hip_bfloat162 h; unsigned int u; } c;
    c.h = __float22bfloat162_rn(make_float2(a, b));
    return c.u;
}

#define NRES 320
#define NN   102400
#define CCH  128
#define NPAD 328   // 320 + 8: 164 dw row stride, 2-way banks on b128 reads
#define PPAD 40    // 32-col half-phase + 8 pad

#define LOG2E 1.4426950408889634f
#define QSCALE (0.17677669529663687f * 1.4426950408889634f)

// ---------------- Kernel 1: LayerNorm -> xn(bf16) + bterm (log2e-scaled) ----------------
__global__ __launch_bounds__(256) void k_ln_bias(
    const float* __restrict__ x2d, const float* __restrict__ ln_g,
    const float* __restrict__ ln_b, const float* __restrict__ wb,
    unsigned short* __restrict__ xn, float* __restrict__ bterm)
{
    int wave = threadIdx.x >> 6, lane = threadIdx.x & 63;
    int r = blockIdx.x * 4 + wave;
    int c0 = lane * 2;
    float2 x = *(const float2*)(x2d + (size_t)r * CCH + c0);
    float s = x.x + x.y, sq = x.x * x.x + x.y * x.y;
    #pragma unroll
    for (int m = 1; m < 64; m <<= 1) { s += __shfl_xor(s, m, 64); sq += __shfl_xor(sq, m, 64); }
    float mu = s * (1.0f / 128.0f);
    float var = sq * (1.0f / 128.0f) - mu * mu;
    float rstd = rsqrtf(var + 1e-5f);
    float xn0 = (x.x - mu) * rstd * ln_g[c0] + ln_b[c0];
    float xn1 = (x.y - mu) * rstd * ln_g[c0 + 1] + ln_b[c0 + 1];
    *(unsigned int*)(xn + (size_t)r * CCH + c0) = pk2bf(xn0, xn1);
    float4 w0 = *(const float4*)(wb + c0 * 4);
    float4 w1 = *(const float4*)(wb + c0 * 4 + 4);
    float b0 = xn0 * w0.x + xn1 * w1.x;
    float b1 = xn0 * w0.y + xn1 * w1.y;
    float b2 = xn0 * w0.z + xn1 * w1.z;
    float b3 = xn0 * w0.w + xn1 * w1.w;
    #pragma unroll
    for (int m = 1; m < 64; m <<= 1) {
        b0 += __shfl_xor(b0, m, 64); b1 += __shfl_xor(b1, m, 64);
        b2 += __shfl_xor(b2, m, 64); b3 += __shfl_xor(b3, m, 64);
    }
    if (lane == 0) {
        bterm[0 * NN + r] = b0 * LOG2E; bterm[1 * NN + r] = b1 * LOG2E;
        bterm[2 * NN + r] = b2 * LOG2E; bterm[3 * NN + r] = b3 * LOG2E;
    }
}

// ---------------- Kernel 2: qkvg = xn @ W[nt] (grid.y = nt; conflict-free B staging) ----------------
__global__ __launch_bounds__(256) void k_proj(
    const unsigned short* __restrict__ xn,
    const float* __restrict__ wq, const float* __restrict__ wk,
    const float* __restrict__ wv, const float* __restrict__ wg,
    const float* __restrict__ bg,
    unsigned short* __restrict__ qkvg)
{
    __shared__ unsigned short A[128][136];
    __shared__ unsigned short Bt[128][136];   // Bt[n][k]
    int m0 = blockIdx.x * 128;
    int nt = blockIdx.y;
    int t = threadIdx.x;
    const float* wsrc = (nt == 0) ? wq : (nt == 1) ? wk : (nt == 2) ? wv : wg;
    #pragma unroll
    for (int it = 0; it < 8; ++it) {
        int idx = it * 256 + t;
        int row = idx >> 4, chunk = idx & 15;
        *(bf16x8*)(&A[row][chunk * 8]) = *(const bf16x8*)(xn + (size_t)(m0 + row) * CCH + chunk * 8);
    }
    {
        int n = t & 127, p = t >> 7;
        const float* col = wsrc + n;
        #pragma unroll
        for (int q = 0; q < 8; ++q) {
            int k0 = p * 64 + q * 8;
            union { unsigned int u[4]; bf16x8 v; } pk;
            #pragma unroll
            for (int z = 0; z < 4; ++z)
                pk.u[z] = pk2bf(col[(size_t)(k0 + 2 * z) * 128], col[(size_t)(k0 + 2 * z + 1) * 128]);
            *(bf16x8*)(&Bt[n][k0]) = pk.v;
        }
    }
    __syncthreads();
    int wave = t >> 6, lane = t & 63;
    int wr = (wave >> 1) * 64, wc = (wave & 1) * 64;
    int li = lane & 15, lk = (lane >> 4) * 8;
    f32x4 acc[4][4] = {};
    #pragma unroll
    for (int kk = 0; kk < 4; ++kk) {
        bf16x8 af[4], bfr[4];
        #pragma unroll
        for (int i = 0; i < 4; ++i) af[i] = *(const bf16x8*)(&A[wr + i * 16 + li][kk * 32 + lk]);
        #pragma unroll
        for (int j = 0; j < 4; ++j) bfr[j] = *(const bf16x8*)(&Bt[wc + j * 16 + li][kk * 32 + lk]);
        __builtin_amdgcn_s_setprio(1);
        #pragma unroll
        for (int i = 0; i < 4; ++i)
            #pragma unroll
            for (int j = 0; j < 4; ++j)
                acc[i][j] = __builtin_amdgcn_mfma_f32_16x16x32_bf16(af[i], bfr[j], acc[i][j], 0, 0, 0);
        __builtin_amdgcn_s_setprio(0);
    }
    int rbase = (lane >> 4) * 4;
    bool isg = (nt == 3), isq = (nt == 0);
    #pragma unroll
    for (int i = 0; i < 4; ++i) {
        #pragma unroll
        for (int j = 0; j < 4; ++j) {
            int col = wc + j * 16 + li;
            int gcol = nt * 128 + col;
            #pragma unroll
            for (int r = 0; r < 4; ++r) {
                int grow = m0 + wr + i * 16 + rbase + r;
                float v = acc[i][j][r];
                if (isg) { v += bg[col]; v = 1.0f / (1.0f + __expf(-v)); }
                if (isq) v *= QSCALE;
                qkvg[(size_t)grow * 512 + gcol] = f2bf(v);
            }
        }
    }
}

// ---------------- Kernel 3: fused attention per (m,h), online softmax, 5×64 phases, 32-col PV ----------------
__global__ __launch_bounds__(256) void k_attn(
    const unsigned short* __restrict__ qkvg,
    const float* __restrict__ bterm,
    const float* __restrict__ mask,
    unsigned short* __restrict__ opre)
{
    __shared__ unsigned short Kl[320][40];     // K rows [j][dc]
    __shared__ unsigned short VT[32][NPAD];    // V transposed [dc][j]
    __shared__ unsigned short Pl[4][16][PPAD]; // per-wave P, one 32-col half-phase at a time
    __shared__ float mb[320];
    int bid = blockIdx.x;
    int m = bid >> 2, h = bid & 3;
    int t = threadIdx.x;
    size_t base = (size_t)m * NRES * 512;
    for (int j = t; j < NRES; j += 256) {
        const bf16x8* src = (const bf16x8*)(qkvg + base + (size_t)j * 512 + 128 + h * 32);
        bf16x8* dst = (bf16x8*)(&Kl[j][0]);
        dst[0] = src[0]; dst[1] = src[1]; dst[2] = src[2]; dst[3] = src[3];
    }
    {
        int dc = t & 31, jg = t >> 5;
        #pragma unroll 8
        for (int jj = 0; jj < 40; jj += 2) {
            int j = jg * 40 + jj;
            unsigned short v0 = qkvg[base + (size_t)j * 512 + 256 + h * 32 + dc];
            unsigned short v1 = qkvg[base + (size_t)(j + 1) * 512 + 256 + h * 32 + dc];
            *(unsigned int*)(&VT[dc][j]) = (unsigned int)v0 | ((unsigned int)v1 << 16);
        }
    }
    for (int j = t; j < NRES; j += 256) mb[j] = (100000.0f * LOG2E) * (mask[(size_t)m * NRES + j] - 1.0f);
    __syncthreads();

    int wave = t >> 6, lane = t & 63;
    int li = lane & 15, lg = lane >> 4;
    for (int c = 0; c < 5; ++c) {
        int i0 = wave * 80 + c * 16;
        int i = i0 + li;
        size_t qrow = base + (size_t)i * 512;
        bf16x8 qf = *(const bf16x8*)(qkvg + qrow + h * 32 + lg * 8);
        const float* brow = bterm + (size_t)h * NN + (size_t)i * NRES;
        f32x4 z = {0.f, 0.f, 0.f, 0.f};
        float mrun = -3.0e38f, sum = 0.0f;
        f32x4 o0 = {0.f, 0.f, 0.f, 0.f}, o1 = {0.f, 0.f, 0.f, 0.f};
        #pragma unroll 1
        for (int ph = 0; ph < 5; ++ph) {
            f32x4 st[4];
            __builtin_amdgcn_s_setprio(1);
            #pragma unroll
            for (int jf = 0; jf < 4; ++jf) {
                bf16x8 kf = *(const bf16x8*)(&Kl[ph * 64 + jf * 16 + li][lg * 8]);
                st[jf] = __builtin_amdgcn_mfma_f32_16x16x32_bf16(kf, qf, z, 0, 0, 0);
            }
            __builtin_amdgcn_s_setprio(0);
            float mx = mrun;
            #pragma unroll
            for (int jf = 0; jf < 4; ++jf) {
                int j0 = ph * 64 + jf * 16 + lg * 4;
                float4 bb = *(const float4*)(brow + j0);
                float4 mm = *(const float4*)(&mb[j0]);
                st[jf][0] += bb.x + mm.x;
                st[jf][1] += bb.y + mm.y;
                st[jf][2] += bb.z + mm.z;
                st[jf][3] += bb.w + mm.w;
                mx = fmaxf(mx, fmaxf(fmaxf(st[jf][0], st[jf][1]), fmaxf(st[jf][2], st[jf][3])));
            }
            mx = fmaxf(mx, __shfl_xor(mx, 16, 64));
            mx = fmaxf(mx, __shfl_xor(mx, 32, 64));
            if (ph) {
                float corr = __builtin_amdgcn_exp2f(mrun - mx);
                sum *= corr;
                #pragma unroll
                for (int r = 0; r < 4; ++r) { o0[r] *= corr; o1[r] *= corr; }
            }
            mrun = mx;
            #pragma unroll
            for (int half = 0; half < 2; ++half) {
                #pragma unroll
                for (int jf2 = 0; jf2 < 2; ++jf2) {
                    int jf = half * 2 + jf2;
                    float p0 = __builtin_amdgcn_exp2f(st[jf][0] - mx);
                    float p1 = __builtin_amdgcn_exp2f(st[jf][1] - mx);
                    float p2 = __builtin_amdgcn_exp2f(st[jf][2] - mx);
                    float p3 = __builtin_amdgcn_exp2f(st[jf][3] - mx);
                    sum += (p0 + p1) + (p2 + p3);
                    unsigned int* dst = (unsigned int*)(&Pl[wave][li][jf2 * 16 + lg * 4]);
                    dst[0] = pk2bf(p0, p1); dst[1] = pk2bf(p2, p3);
                }
                __builtin_amdgcn_s_setprio(1);
                {
                    bf16x8 pf = *(const bf16x8*)(&Pl[wave][li][lg * 8]);
                    bf16x8 va = *(const bf16x8*)(&VT[li][ph * 64 + half * 32 + lg * 8]);
                    bf16x8 vb = *(const bf16x8*)(&VT[16 + li][ph * 64 + half * 32 + lg * 8]);
                    o0 = __builtin_amdgcn_mfma_f32_16x16x32_bf16(va, pf, o0, 0, 0, 0);
                    o1 = __builtin_amdgcn_mfma_f32_16x16x32_bf16(vb, pf, o1, 0, 0, 0);
                }
                __builtin_amdgcn_s_setprio(0);
            }
        }
        sum += __shfl_xor(sum, 16, 64);
        sum += __shfl_xor(sum, 32, 64);
        float inv = 1.0f / sum;
        size_t orow = ((size_t)m * NRES + i) * CCH + h * 32;
        #pragma unroll
        for (int df = 0; df < 2; ++df) {
            f32x4 o = df ? o1 : o0;
            int dcb = df * 16 + lg * 4;
            u16x4 gv = *(const u16x4*)(qkvg + qrow + 384 + h * 32 + dcb);
            u16x4 ov;
            #pragma unroll
            for (int r = 0; r < 4; ++r) ov[r] = f2bf(o[r] * inv * bf2f(gv[r]));
            *(u16x4*)(opre + orow + dcb) = ov;
        }
    }
}

// ---------------- Kernel 4: out = opre @ wo + bo (f32 out; conflict-free B staging) ----------------
__global__ __launch_bounds__(256) void k_out(
    const unsigned short* __restrict__ opre, const float* __restrict__ wo,
    const float* __restrict__ bo, float* __restrict__ out)
{
    __shared__ unsigned short A[128][136];
    __shared__ unsigned short Bt[128][136];
    int m0 = blockIdx.x * 128;
    int t = threadIdx.x;
    #pragma unroll
    for (int it = 0; it < 8; ++it) {
        int idx = it * 256 + t;
        int row = idx >> 4, chunk = idx & 15;
        *(bf16x8*)(&A[row][chunk * 8]) = *(const bf16x8*)(opre + (size_t)(m0 + row) * CCH + chunk * 8);
    }
    {
        int n = t & 127, p = t >> 7;
        const float* col = wo + n;
        #pragma unroll
        for (int q = 0; q < 8; ++q) {
            int k0 = p * 64 + q * 8;
            union { unsigned int u[4]; bf16x8 v; } pk;
            #pragma unroll
            for (int z = 0; z < 4; ++z)
                pk.u[z] = pk2bf(col[(size_t)(k0 + 2 * z) * 128], col[(size_t)(k0 + 2 * z + 1) * 128]);
            *(bf16x8*)(&Bt[n][k0]) = pk.v;
        }
    }
    __syncthreads();
    int wave = t >> 6, lane = t & 63;
    int wr = (wave >> 1) * 64, wc = (wave & 1) * 64;
    int li = lane & 15, lk = (lane >> 4) * 8;
    f32x4 acc[4][4] = {};
    #pragma unroll
    for (int kk = 0; kk < 4; ++kk) {
        bf16x8 af[4], bfr[4];
        #pragma unroll
        for (int i = 0; i < 4; ++i) af[i] = *(const bf16x8*)(&A[wr + i * 16 + li][kk * 32 + lk]);
        #pragma unroll
        for (int j = 0; j < 4; ++j) bfr[j] = *(const bf16x8*)(&Bt[wc + j * 16 + li][kk * 32 + lk]);
        __builtin_amdgcn_s_setprio(1);
        #pragma unroll
        for (int i = 0; i < 4; ++i)
            #pragma unroll
            for (int j = 0; j < 4; ++j)
                acc[i][j] = __builtin_amdgcn_mfma_f32_16x16x32_bf16(af[i], bfr[j], acc[i][j], 0, 0, 0);
        __builtin_amdgcn_s_setprio(0);
    }
    int rbase = (lane >> 4) * 4;
    #pragma unroll
    for (int i = 0; i < 4; ++i) {
        #pragma unroll
        for (int j = 0; j < 4; ++j) {
            int col = wc + j * 16 + li;
            #pragma unroll
            for (int r = 0; r < 4; ++r) {
                int grow = m0 + wr + i * 16 + rbase + r;
                out[(size_t)grow * CCH + col] = acc[i][j][r] + bo[col];
            }
        }
    }
}

extern "C" void kernel_launch(void* const* d_in, const int* in_sizes, int n_in,
                              void* d_out, int out_size, void* d_ws, size_t ws_size,
                              hipStream_t stream) {
    const float* x2d  = (const float*)d_in[0];
    const float* mask = (const float*)d_in[1];
    const float* ln_g = (const float*)d_in[2];
    const float* ln_b = (const float*)d_in[3];
    const float* wq   = (const float*)d_in[4];
    const float* wk   = (const float*)d_in[5];
    const float* wv   = (const float*)d_in[6];
    const float* wb   = (const float*)d_in[7];
    const float* wg   = (const float*)d_in[8];
    const float* bg   = (const float*)d_in[9];
    const float* wo   = (const float*)d_in[10];
    const float* bo   = (const float*)d_in[11];
    float* out = (float*)d_out;

    char* ws = (char*)d_ws;
    unsigned short* xn    = (unsigned short*)ws;                                 // 26,214,400 B (reused as opre)
    unsigned short* qkvg  = (unsigned short*)(ws + 26214400);                    // 104,857,600 B
    float*          bterm = (float*)(ws + 26214400 + 104857600);                 // 1,638,400 B
    unsigned short* opre  = xn;

    if (ws_size < (size_t)(26214400 + 104857600 + 1638400)) return;

    k_ln_bias<<<25600, 256, 0, stream>>>(x2d, ln_g, ln_b, wb, xn, bterm);
    k_proj<<<dim3(800, 4), 256, 0, stream>>>(xn, wq, wk, wv, wg, bg, qkvg);
    k_attn<<<1280, 256, 0, stream>>>(qkvg, bterm, mask, opre);
    k_out<<<800, 256, 0, stream>>>(opre, wo, bo, out);
}

// Round 9
// 210.476 us; speedup vs baseline: 2.1975x; 1.0148x over previous
//
#include <hip/hip_runtime.h>
#include <hip/hip_bf16.h>

typedef __attribute__((ext_vector_type(8))) short bf16x8;
typedef __attribute__((ext_vector_type(4))) float f32x4;
typedef __attribute__((ext_vector_type(4))) unsigned short u16x4;

#define DEVI static __device__ __forceinline__

DEVI float bf2f(unsigned short u) {
    union { unsigned int ui; float f; } c; c.ui = ((unsigned int)u) << 16; return c.f;
}
DEVI unsigned short f2bf(float f) {
    union { float f; unsigned int ui; } c; c.f = f;
    unsigned int u = c.ui;
    u += 0x7FFFu + ((u >> 16) & 1u);
    return (unsigned short)(u >> 16);
}
DEVI unsigned int pk2bf(float a, float b) {   // v_cvt_pk_bf16_f32 via compiler
    union { __hip_bfloat162 h; unsigned int u; } c;
    c.h = __float22bfloat162_rn(make_float2(a, b));
    return c.u;
}

#define NRES 320
#define NN   102400
#define CCH  128
#define NPAD 328   // 164 dw row stride, 2-way banks on b128 reads
#define PPAD 40    // 32-col half-phase + 8 pad
#define ABLK 640   // k_attn block: 10 waves

#define LOG2E 1.4426950408889634f
#define QSCALE (0.17677669529663687f * 1.4426950408889634f)

// ---------------- Kernel 1: LayerNorm -> xn(bf16) + bterm (log2e-scaled) ----------------
__global__ __launch_bounds__(256) void k_ln_bias(
    const float* __restrict__ x2d, const float* __restrict__ ln_g,
    const float* __restrict__ ln_b, const float* __restrict__ wb,
    unsigned short* __restrict__ xn, float* __restrict__ bterm)
{
    int wave = threadIdx.x >> 6, lane = threadIdx.x & 63;
    int r = blockIdx.x * 4 + wave;
    int c0 = lane * 2;
    float2 x = *(const float2*)(x2d + (size_t)r * CCH + c0);
    float s = x.x + x.y, sq = x.x * x.x + x.y * x.y;
    #pragma unroll
    for (int m = 1; m < 64; m <<= 1) { s += __shfl_xor(s, m, 64); sq += __shfl_xor(sq, m, 64); }
    float mu = s * (1.0f / 128.0f);
    float var = sq * (1.0f / 128.0f) - mu * mu;
    float rstd = rsqrtf(var + 1e-5f);
    float xn0 = (x.x - mu) * rstd * ln_g[c0] + ln_b[c0];
    float xn1 = (x.y - mu) * rstd * ln_g[c0 + 1] + ln_b[c0 + 1];
    *(unsigned int*)(xn + (size_t)r * CCH + c0) = pk2bf(xn0, xn1);
    float4 w0 = *(const float4*)(wb + c0 * 4);
    float4 w1 = *(const float4*)(wb + c0 * 4 + 4);
    float b0 = xn0 * w0.x + xn1 * w1.x;
    float b1 = xn0 * w0.y + xn1 * w1.y;
    float b2 = xn0 * w0.z + xn1 * w1.z;
    float b3 = xn0 * w0.w + xn1 * w1.w;
    #pragma unroll
    for (int m = 1; m < 64; m <<= 1) {
        b0 += __shfl_xor(b0, m, 64); b1 += __shfl_xor(b1, m, 64);
        b2 += __shfl_xor(b2, m, 64); b3 += __shfl_xor(b3, m, 64);
    }
    if (lane == 0) {
        bterm[0 * NN + r] = b0 * LOG2E; bterm[1 * NN + r] = b1 * LOG2E;
        bterm[2 * NN + r] = b2 * LOG2E; bterm[3 * NN + r] = b3 * LOG2E;
    }
}

// ---------------- Kernel 2: qkvg = xn @ W[nt] (grid.y = nt; conflict-free B staging) ----------------
__global__ __launch_bounds__(256) void k_proj(
    const unsigned short* __restrict__ xn,
    const float* __restrict__ wq, const float* __restrict__ wk,
    const float* __restrict__ wv, const float* __restrict__ wg,
    const float* __restrict__ bg,
    unsigned short* __restrict__ qkvg)
{
    __shared__ unsigned short A[128][136];
    __shared__ unsigned short Bt[128][136];   // Bt[n][k]
    int m0 = blockIdx.x * 128;
    int nt = blockIdx.y;
    int t = threadIdx.x;
    const float* wsrc = (nt == 0) ? wq : (nt == 1) ? wk : (nt == 2) ? wv : wg;
    #pragma unroll
    for (int it = 0; it < 8; ++it) {
        int idx = it * 256 + t;
        int row = idx >> 4, chunk = idx & 15;
        *(bf16x8*)(&A[row][chunk * 8]) = *(const bf16x8*)(xn + (size_t)(m0 + row) * CCH + chunk * 8);
    }
    {
        int n = t & 127, p = t >> 7;
        const float* col = wsrc + n;
        #pragma unroll
        for (int q = 0; q < 8; ++q) {
            int k0 = p * 64 + q * 8;
            union { unsigned int u[4]; bf16x8 v; } pk;
            #pragma unroll
            for (int z = 0; z < 4; ++z)
                pk.u[z] = pk2bf(col[(size_t)(k0 + 2 * z) * 128], col[(size_t)(k0 + 2 * z + 1) * 128]);
            *(bf16x8*)(&Bt[n][k0]) = pk.v;
        }
    }
    __syncthreads();
    int wave = t >> 6, lane = t & 63;
    int wr = (wave >> 1) * 64, wc = (wave & 1) * 64;
    int li = lane & 15, lk = (lane >> 4) * 8;
    f32x4 acc[4][4] = {};
    #pragma unroll
    for (int kk = 0; kk < 4; ++kk) {
        bf16x8 af[4], bfr[4];
        #pragma unroll
        for (int i = 0; i < 4; ++i) af[i] = *(const bf16x8*)(&A[wr + i * 16 + li][kk * 32 + lk]);
        #pragma unroll
        for (int j = 0; j < 4; ++j) bfr[j] = *(const bf16x8*)(&Bt[wc + j * 16 + li][kk * 32 + lk]);
        __builtin_amdgcn_s_setprio(1);
        #pragma unroll
        for (int i = 0; i < 4; ++i)
            #pragma unroll
            for (int j = 0; j < 4; ++j)
                acc[i][j] = __builtin_amdgcn_mfma_f32_16x16x32_bf16(af[i], bfr[j], acc[i][j], 0, 0, 0);
        __builtin_amdgcn_s_setprio(0);
    }
    int rbase = (lane >> 4) * 4;
    bool isg = (nt == 3), isq = (nt == 0);
    #pragma unroll
    for (int i = 0; i < 4; ++i) {
        #pragma unroll
        for (int j = 0; j < 4; ++j) {
            int col = wc + j * 16 + li;
            int gcol = nt * 128 + col;
            #pragma unroll
            for (int r = 0; r < 4; ++r) {
                int grow = m0 + wr + i * 16 + rbase + r;
                float v = acc[i][j][r];
                if (isg) { v += bg[col]; v = 1.0f / (1.0f + __expf(-v)); }
                if (isq) v *= QSCALE;
                qkvg[(size_t)grow * 512 + gcol] = f2bf(v);
            }
        }
    }
}

// ---------------- Kernel 3: fused attention per (m,h): 10 waves, 64 rows/wave ----------------
__global__ __launch_bounds__(ABLK) void k_attn(
    const unsigned short* __restrict__ qkvg,
    const float* __restrict__ bterm,
    const float* __restrict__ mask,
    unsigned short* __restrict__ opre)
{
    __shared__ unsigned short Kl[320][40];      // K rows [j][dc]
    __shared__ unsigned short VT[32][NPAD];     // V transposed [dc][j]
    __shared__ unsigned short Pl[10][16][PPAD]; // per-wave P, one 32-col half-phase at a time
    __shared__ float mb[320];
    int bid = blockIdx.x;
    int m = bid >> 2, h = bid & 3;
    int t = threadIdx.x;
    size_t base = (size_t)m * NRES * 512;
    for (int j = t; j < NRES; j += ABLK) {
        const bf16x8* src = (const bf16x8*)(qkvg + base + (size_t)j * 512 + 128 + h * 32);
        bf16x8* dst = (bf16x8*)(&Kl[j][0]);
        dst[0] = src[0]; dst[1] = src[1]; dst[2] = src[2]; dst[3] = src[3];
    }
    {
        int dc = t & 31, jg = t >> 5;   // jg in 0..19, 16 cols each
        #pragma unroll 8
        for (int jj = 0; jj < 16; jj += 2) {
            int j = jg * 16 + jj;
            unsigned short v0 = qkvg[base + (size_t)j * 512 + 256 + h * 32 + dc];
            unsigned short v1 = qkvg[base + (size_t)(j + 1) * 512 + 256 + h * 32 + dc];
            *(unsigned int*)(&VT[dc][j]) = (unsigned int)v0 | ((unsigned int)v1 << 16);
        }
    }
    for (int j = t; j < NRES; j += ABLK) mb[j] = (100000.0f * LOG2E) * (mask[(size_t)m * NRES + j] - 1.0f);
    __syncthreads();

    int wave = t >> 6, lane = t & 63;
    int li = lane & 15, lg = lane >> 4;
    for (int c = 0; c < 2; ++c) {
        int i0 = wave * 32 + c * 16;
        int i = i0 + li;
        size_t qrow = base + (size_t)i * 512;
        bf16x8 qf = *(const bf16x8*)(qkvg + qrow + h * 32 + lg * 8);
        const float* brow = bterm + (size_t)h * NN + (size_t)i * NRES;
        f32x4 z = {0.f, 0.f, 0.f, 0.f};
        float mrun = -3.0e38f, sum = 0.0f;
        f32x4 o0 = {0.f, 0.f, 0.f, 0.f}, o1 = {0.f, 0.f, 0.f, 0.f};
        #pragma unroll 1
        for (int ph = 0; ph < 5; ++ph) {
            f32x4 st[4];
            __builtin_amdgcn_s_setprio(1);
            #pragma unroll
            for (int jf = 0; jf < 4; ++jf) {
                bf16x8 kf = *(const bf16x8*)(&Kl[ph * 64 + jf * 16 + li][lg * 8]);
                st[jf] = __builtin_amdgcn_mfma_f32_16x16x32_bf16(kf, qf, z, 0, 0, 0);
            }
            __builtin_amdgcn_s_setprio(0);
            float mx = mrun;
            #pragma unroll
            for (int jf = 0; jf < 4; ++jf) {
                int j0 = ph * 64 + jf * 16 + lg * 4;
                float4 bb = *(const float4*)(brow + j0);
                float4 mm = *(const float4*)(&mb[j0]);
                st[jf][0] += bb.x + mm.x;
                st[jf][1] += bb.y + mm.y;
                st[jf][2] += bb.z + mm.z;
                st[jf][3] += bb.w + mm.w;
                mx = fmaxf(mx, fmaxf(fmaxf(st[jf][0], st[jf][1]), fmaxf(st[jf][2], st[jf][3])));
            }
            mx = fmaxf(mx, __shfl_xor(mx, 16, 64));
            mx = fmaxf(mx, __shfl_xor(mx, 32, 64));
            if (ph) {
                float corr = __builtin_amdgcn_exp2f(mrun - mx);
                sum *= corr;
                #pragma unroll
                for (int r = 0; r < 4; ++r) { o0[r] *= corr; o1[r] *= corr; }
            }
            mrun = mx;
            #pragma unroll
            for (int half = 0; half < 2; ++half) {
                #pragma unroll
                for (int jf2 = 0; jf2 < 2; ++jf2) {
                    int jf = half * 2 + jf2;
                    float p0 = __builtin_amdgcn_exp2f(st[jf][0] - mx);
                    float p1 = __builtin_amdgcn_exp2f(st[jf][1] - mx);
                    float p2 = __builtin_amdgcn_exp2f(st[jf][2] - mx);
                    float p3 = __builtin_amdgcn_exp2f(st[jf][3] - mx);
                    sum += (p0 + p1) + (p2 + p3);
                    unsigned int* dst = (unsigned int*)(&Pl[wave][li][jf2 * 16 + lg * 4]);
                    dst[0] = pk2bf(p0, p1); dst[1] = pk2bf(p2, p3);
                }
                __builtin_amdgcn_s_setprio(1);
                {
                    bf16x8 pf = *(const bf16x8*)(&Pl[wave][li][lg * 8]);
                    bf16x8 va = *(const bf16x8*)(&VT[li][ph * 64 + half * 32 + lg * 8]);
                    bf16x8 vb = *(const bf16x8*)(&VT[16 + li][ph * 64 + half * 32 + lg * 8]);
                    o0 = __builtin_amdgcn_mfma_f32_16x16x32_bf16(va, pf, o0, 0, 0, 0);
                    o1 = __builtin_amdgcn_mfma_f32_16x16x32_bf16(vb, pf, o1, 0, 0, 0);
                }
                __builtin_amdgcn_s_setprio(0);
            }
        }
        sum += __shfl_xor(sum, 16, 64);
        sum += __shfl_xor(sum, 32, 64);
        float inv = 1.0f / sum;
        size_t orow = ((size_t)m * NRES + i) * CCH + h * 32;
        #pragma unroll
        for (int df = 0; df < 2; ++df) {
            f32x4 o = df ? o1 : o0;
            int dcb = df * 16 + lg * 4;
            u16x4 gv = *(const u16x4*)(qkvg + qrow + 384 + h * 32 + dcb);
            u16x4 ov;
            #pragma unroll
            for (int r = 0; r < 4; ++r) ov[r] = f2bf(o[r] * inv * bf2f(gv[r]));
            *(u16x4*)(opre + orow + dcb) = ov;
        }
    }
}

// ---------------- Kernel 4: out = opre @ wo + bo (f32 out; conflict-free B staging) ----------------
__global__ __launch_bounds__(256) void k_out(
    const unsigned short* __restrict__ opre, const float* __restrict__ wo,
    const float* __restrict__ bo, float* __restrict__ out)
{
    __shared__ unsigned short A[128][136];
    __shared__ unsigned short Bt[128][136];
    int m0 = blockIdx.x * 128;
    int t = threadIdx.x;
    #pragma unroll
    for (int it = 0; it < 8; ++it) {
        int idx = it * 256 + t;
        int row = idx >> 4, chunk = idx & 15;
        *(bf16x8*)(&A[row][chunk * 8]) = *(const bf16x8*)(opre + (size_t)(m0 + row) * CCH + chunk * 8);
    }
    {
        int n = t & 127, p = t >> 7;
        const float* col = wo + n;
        #pragma unroll
        for (int q = 0; q < 8; ++q) {
            int k0 = p * 64 + q * 8;
            union { unsigned int u[4]; bf16x8 v; } pk;
            #pragma unroll
            for (int z = 0; z < 4; ++z)
                pk.u[z] = pk2bf(col[(size_t)(k0 + 2 * z) * 128], col[(size_t)(k0 + 2 * z + 1) * 128]);
            *(bf16x8*)(&Bt[n][k0]) = pk.v;
        }
    }
    __syncthreads();
    int wave = t >> 6, lane = t & 63;
    int wr = (wave >> 1) * 64, wc = (wave & 1) * 64;
    int li = lane & 15, lk = (lane >> 4) * 8;
    f32x4 acc[4][4] = {};
    #pragma unroll
    for (int kk = 0; kk < 4; ++kk) {
        bf16x8 af[4], bfr[4];
        #pragma unroll
        for (int i = 0; i < 4; ++i) af[i] = *(const bf16x8*)(&A[wr + i * 16 + li][kk * 32 + lk]);
        #pragma unroll
        for (int j = 0; j < 4; ++j) bfr[j] = *(const bf16x8*)(&Bt[wc + j * 16 + li][kk * 32 + lk]);
        __builtin_amdgcn_s_setprio(1);
        #pragma unroll
        for (int i = 0; i < 4; ++i)
            #pragma unroll
            for (int j = 0; j < 4; ++j)
                acc[i][j] = __builtin_amdgcn_mfma_f32_16x16x32_bf16(af[i], bfr[j], acc[i][j], 0, 0, 0);
        __builtin_amdgcn_s_setprio(0);
    }
    int rbase = (lane >> 4) * 4;
    #pragma unroll
    for (int i = 0; i < 4; ++i) {
        #pragma unroll
        for (int j = 0; j < 4; ++j) {
            int col = wc + j * 16 + li;
            #pragma unroll
            for (int r = 0; r < 4; ++r) {
                int grow = m0 + wr + i * 16 + rbase + r;
                out[(size_t)grow * CCH + col] = acc[i][j][r] + bo[col];
            }
        }
    }
}

extern "C" void kernel_launch(void* const* d_in, const int* in_sizes, int n_in,
                              void* d_out, int out_size, void* d_ws, size_t ws_size,
                              hipStream_t stream) {
    const float* x2d  = (const float*)d_in[0];
    const float* mask = (const float*)d_in[1];
    const float* ln_g = (const float*)d_in[2];
    const float* ln_b = (const float*)d_in[3];
    const float* wq   = (const float*)d_in[4];
    const float* wk   = (const float*)d_in[5];
    const float* wv   = (const float*)d_in[6];
    const float* wb   = (const float*)d_in[7];
    const float* wg   = (const float*)d_in[8];
    const float* bg   = (const float*)d_in[9];
    const float* wo   = (const float*)d_in[10];
    const float* bo   = (const float*)d_in[11];
    float* out = (float*)d_out;

    char* ws = (char*)d_ws;
    unsigned short* xn    = (unsigned short*)ws;                                 // 26,214,400 B (reused as opre)
    unsigned short* qkvg  = (unsigned short*)(ws + 26214400);                    // 104,857,600 B
    float*          bterm = (float*)(ws + 26214400 + 104857600);                 // 1,638,400 B
    unsigned short* opre  = xn;

    if (ws_size < (size_t)(26214400 + 104857600 + 1638400)) return;

    k_ln_bias<<<25600, 256, 0, stream>>>(x2d, ln_g, ln_b, wb, xn, bterm);
    k_proj<<<dim3(800, 4), 256, 0, stream>>>(xn, wq, wk, wv, wg, bg, qkvg);
    k_attn<<<1280, ABLK, 0, stream>>>(qkvg, bterm, mask, opre);
    k_out<<<800, 256, 0, stream>>>(opre, wo, bo, out);
}

// Round 10
// 210.427 us; speedup vs baseline: 2.1980x; 1.0002x over previous
//
#include <hip/hip_runtime.h>
#include <hip/hip_bf16.h>

typedef __attribute__((ext_vector_type(8))) short bf16x8;
typedef __attribute__((ext_vector_type(4))) float f32x4;
typedef __attribute__((ext_vector_type(4))) unsigned short u16x4;

#define DEVI static __device__ __forceinline__

DEVI float bf2f(unsigned short u) {
    union { unsigned int ui; float f; } c; c.ui = ((unsigned int)u) << 16; return c.f;
}
DEVI unsigned short f2bf(float f) {
    union { float f; unsigned int ui; } c; c.f = f;
    unsigned int u = c.ui;
    u += 0x7FFFu + ((u >> 16) & 1u);
    return (unsigned short)(u >> 16);
}
DEVI unsigned int pk2bf(float a, float b) {   // v_cvt_pk_bf16_f32 via compiler
    union { __hip_bfloat162 h; unsigned int u; } c;
    c.h = __float22bfloat162_rn(make_float2(a, b));
    return c.u;
}

#define NRES 320
#define NN   102400
#define CCH  128
#define NPAD 328   // 164 dw row stride, 2-way banks on b128 reads
#define PPAD 40    // 32-col half-phase + 8 pad
#define ABLK 640   // k_attn block: 10 waves, 32 rows each

#define LOG2E 1.4426950408889634f
#define QSCALE (0.17677669529663687f * 1.4426950408889634f)

// ---------------- Kernel 1: LayerNorm -> xn(bf16) + bterm (log2e-scaled) ----------------
__global__ __launch_bounds__(256) void k_ln_bias(
    const float* __restrict__ x2d, const float* __restrict__ ln_g,
    const float* __restrict__ ln_b, const float* __restrict__ wb,
    unsigned short* __restrict__ xn, float* __restrict__ bterm)
{
    int wave = threadIdx.x >> 6, lane = threadIdx.x & 63;
    int r = blockIdx.x * 4 + wave;
    int c0 = lane * 2;
    float2 x = *(const float2*)(x2d + (size_t)r * CCH + c0);
    float s = x.x + x.y, sq = x.x * x.x + x.y * x.y;
    #pragma unroll
    for (int m = 1; m < 64; m <<= 1) { s += __shfl_xor(s, m, 64); sq += __shfl_xor(sq, m, 64); }
    float mu = s * (1.0f / 128.0f);
    float var = sq * (1.0f / 128.0f) - mu * mu;
    float rstd = rsqrtf(var + 1e-5f);
    float xn0 = (x.x - mu) * rstd * ln_g[c0] + ln_b[c0];
    float xn1 = (x.y - mu) * rstd * ln_g[c0 + 1] + ln_b[c0 + 1];
    *(unsigned int*)(xn + (size_t)r * CCH + c0) = pk2bf(xn0, xn1);
    float4 w0 = *(const float4*)(wb + c0 * 4);
    float4 w1 = *(const float4*)(wb + c0 * 4 + 4);
    float b0 = xn0 * w0.x + xn1 * w1.x;
    float b1 = xn0 * w0.y + xn1 * w1.y;
    float b2 = xn0 * w0.z + xn1 * w1.z;
    float b3 = xn0 * w0.w + xn1 * w1.w;
    #pragma unroll
    for (int m = 1; m < 64; m <<= 1) {
        b0 += __shfl_xor(b0, m, 64); b1 += __shfl_xor(b1, m, 64);
        b2 += __shfl_xor(b2, m, 64); b3 += __shfl_xor(b3, m, 64);
    }
    if (lane == 0) {
        bterm[0 * NN + r] = b0 * LOG2E; bterm[1 * NN + r] = b1 * LOG2E;
        bterm[2 * NN + r] = b2 * LOG2E; bterm[3 * NN + r] = b3 * LOG2E;
    }
}

// ---------------- Kernel 2: qkvg = xn @ W[nt] (grid.y = nt; conflict-free B staging) ----------------
__global__ __launch_bounds__(256) void k_proj(
    const unsigned short* __restrict__ xn,
    const float* __restrict__ wq, const float* __restrict__ wk,
    const float* __restrict__ wv, const float* __restrict__ wg,
    const float* __restrict__ bg,
    unsigned short* __restrict__ qkvg)
{
    __shared__ unsigned short A[128][136];
    __shared__ unsigned short Bt[128][136];   // Bt[n][k]
    int m0 = blockIdx.x * 128;
    int nt = blockIdx.y;
    int t = threadIdx.x;
    const float* wsrc = (nt == 0) ? wq : (nt == 1) ? wk : (nt == 2) ? wv : wg;
    #pragma unroll
    for (int it = 0; it < 8; ++it) {
        int idx = it * 256 + t;
        int row = idx >> 4, chunk = idx & 15;
        *(bf16x8*)(&A[row][chunk * 8]) = *(const bf16x8*)(xn + (size_t)(m0 + row) * CCH + chunk * 8);
    }
    {
        int n = t & 127, p = t >> 7;
        const float* col = wsrc + n;
        #pragma unroll
        for (int q = 0; q < 8; ++q) {
            int k0 = p * 64 + q * 8;
            union { unsigned int u[4]; bf16x8 v; } pk;
            #pragma unroll
            for (int z = 0; z < 4; ++z)
                pk.u[z] = pk2bf(col[(size_t)(k0 + 2 * z) * 128], col[(size_t)(k0 + 2 * z + 1) * 128]);
            *(bf16x8*)(&Bt[n][k0]) = pk.v;
        }
    }
    __syncthreads();
    int wave = t >> 6, lane = t & 63;
    int wr = (wave >> 1) * 64, wc = (wave & 1) * 64;
    int li = lane & 15, lk = (lane >> 4) * 8;
    f32x4 acc[4][4] = {};
    #pragma unroll
    for (int kk = 0; kk < 4; ++kk) {
        bf16x8 af[4], bfr[4];
        #pragma unroll
        for (int i = 0; i < 4; ++i) af[i] = *(const bf16x8*)(&A[wr + i * 16 + li][kk * 32 + lk]);
        #pragma unroll
        for (int j = 0; j < 4; ++j) bfr[j] = *(const bf16x8*)(&Bt[wc + j * 16 + li][kk * 32 + lk]);
        __builtin_amdgcn_s_setprio(1);
        #pragma unroll
        for (int i = 0; i < 4; ++i)
            #pragma unroll
            for (int j = 0; j < 4; ++j)
                acc[i][j] = __builtin_amdgcn_mfma_f32_16x16x32_bf16(af[i], bfr[j], acc[i][j], 0, 0, 0);
        __builtin_amdgcn_s_setprio(0);
    }
    int rbase = (lane >> 4) * 4;
    bool isg = (nt == 3), isq = (nt == 0);
    #pragma unroll
    for (int i = 0; i < 4; ++i) {
        #pragma unroll
        for (int j = 0; j < 4; ++j) {
            int col = wc + j * 16 + li;
            int gcol = nt * 128 + col;
            #pragma unroll
            for (int r = 0; r < 4; ++r) {
                int grow = m0 + wr + i * 16 + rbase + r;
                float v = acc[i][j][r];
                if (isg) { v += bg[col]; v = 1.0f / (1.0f + __expf(-v)); }
                if (isq) v *= QSCALE;
                qkvg[(size_t)grow * 512 + gcol] = f2bf(v);
            }
        }
    }
}

// ---------------- Kernel 3: fused attention per (m,h): 10 waves, 32 rows/wave, single pass ----------------
__global__ __launch_bounds__(ABLK) void k_attn(
    const unsigned short* __restrict__ qkvg,
    const float* __restrict__ bterm,
    const float* __restrict__ mask,
    unsigned short* __restrict__ opre)
{
    __shared__ unsigned short Kl[320][40];      // K rows [j][dc]
    __shared__ unsigned short VT[32][NPAD];     // V transposed [dc][j]
    __shared__ unsigned short Pl[10][16][PPAD]; // per-wave P, one 32-col half-phase at a time
    __shared__ float mb[320];
    int bid = blockIdx.x;
    int m = bid >> 2, h = bid & 3;
    int t = threadIdx.x;
    size_t base = (size_t)m * NRES * 512;
    // K stage: 4-lane-contiguous 64B segments, all threads busy
    for (int idx = t; idx < NRES * 4; idx += ABLK) {
        int row = idx >> 2, q = idx & 3;
        *(bf16x8*)(&Kl[row][q * 8]) =
            *(const bf16x8*)(qkvg + base + (size_t)row * 512 + 128 + h * 32 + q * 8);
    }
    {
        int dc = t & 31, jg = t >> 5;   // jg in 0..19, 16 cols each
        #pragma unroll 8
        for (int jj = 0; jj < 16; jj += 2) {
            int j = jg * 16 + jj;
            unsigned short v0 = qkvg[base + (size_t)j * 512 + 256 + h * 32 + dc];
            unsigned short v1 = qkvg[base + (size_t)(j + 1) * 512 + 256 + h * 32 + dc];
            *(unsigned int*)(&VT[dc][j]) = (unsigned int)v0 | ((unsigned int)v1 << 16);
        }
    }
    for (int j = t; j < NRES; j += ABLK) mb[j] = (100000.0f * LOG2E) * (mask[(size_t)m * NRES + j] - 1.0f);
    __syncthreads();

    int wave = t >> 6, lane = t & 63;
    int li = lane & 15, lg = lane >> 4;
    int ia = wave * 32 + li, ib = ia + 16;
    size_t qrow_a = base + (size_t)ia * 512, qrow_b = base + (size_t)ib * 512;
    bf16x8 qfa = *(const bf16x8*)(qkvg + qrow_a + h * 32 + lg * 8);
    bf16x8 qfb = *(const bf16x8*)(qkvg + qrow_b + h * 32 + lg * 8);
    const float* brow_a = bterm + (size_t)h * NN + (size_t)ia * NRES;
    const float* brow_b = bterm + (size_t)h * NN + (size_t)ib * NRES;
    f32x4 z = {0.f, 0.f, 0.f, 0.f};
    float mrun_a = -3.0e38f, sum_a = 0.0f;
    float mrun_b = -3.0e38f, sum_b = 0.0f;
    f32x4 oa0 = z, oa1 = z, ob0 = z, ob1 = z;
    #pragma unroll 1
    for (int ph = 0; ph < 5; ++ph) {
        f32x4 sa[4], sb[4];
        __builtin_amdgcn_s_setprio(1);
        #pragma unroll
        for (int jf = 0; jf < 4; ++jf) {
            bf16x8 kf = *(const bf16x8*)(&Kl[ph * 64 + jf * 16 + li][lg * 8]);
            sa[jf] = __builtin_amdgcn_mfma_f32_16x16x32_bf16(kf, qfa, z, 0, 0, 0);
            sb[jf] = __builtin_amdgcn_mfma_f32_16x16x32_bf16(kf, qfb, z, 0, 0, 0);
        }
        __builtin_amdgcn_s_setprio(0);
        float mxa = mrun_a, mxb = mrun_b;
        #pragma unroll
        for (int jf = 0; jf < 4; ++jf) {
            int j0 = ph * 64 + jf * 16 + lg * 4;
            float4 mm = *(const float4*)(&mb[j0]);
            float4 ba = *(const float4*)(brow_a + j0);
            float4 bbv = *(const float4*)(brow_b + j0);
            sa[jf][0] += ba.x + mm.x; sa[jf][1] += ba.y + mm.y;
            sa[jf][2] += ba.z + mm.z; sa[jf][3] += ba.w + mm.w;
            sb[jf][0] += bbv.x + mm.x; sb[jf][1] += bbv.y + mm.y;
            sb[jf][2] += bbv.z + mm.z; sb[jf][3] += bbv.w + mm.w;
            mxa = fmaxf(mxa, fmaxf(fmaxf(sa[jf][0], sa[jf][1]), fmaxf(sa[jf][2], sa[jf][3])));
            mxb = fmaxf(mxb, fmaxf(fmaxf(sb[jf][0], sb[jf][1]), fmaxf(sb[jf][2], sb[jf][3])));
        }
        mxa = fmaxf(mxa, __shfl_xor(mxa, 16, 64));
        mxa = fmaxf(mxa, __shfl_xor(mxa, 32, 64));
        mxb = fmaxf(mxb, __shfl_xor(mxb, 16, 64));
        mxb = fmaxf(mxb, __shfl_xor(mxb, 32, 64));
        if (ph) {
            float ca = __builtin_amdgcn_exp2f(mrun_a - mxa);
            float cb = __builtin_amdgcn_exp2f(mrun_b - mxb);
            sum_a *= ca; sum_b *= cb;
            #pragma unroll
            for (int r = 0; r < 4; ++r) {
                oa0[r] *= ca; oa1[r] *= ca;
                ob0[r] *= cb; ob1[r] *= cb;
            }
        }
        mrun_a = mxa; mrun_b = mxb;
        #pragma unroll
        for (int half = 0; half < 2; ++half) {
            bf16x8 va = *(const bf16x8*)(&VT[li][ph * 64 + half * 32 + lg * 8]);
            bf16x8 vb = *(const bf16x8*)(&VT[16 + li][ph * 64 + half * 32 + lg * 8]);
            // row-group a
            #pragma unroll
            for (int jf2 = 0; jf2 < 2; ++jf2) {
                int jf = half * 2 + jf2;
                float p0 = __builtin_amdgcn_exp2f(sa[jf][0] - mxa);
                float p1 = __builtin_amdgcn_exp2f(sa[jf][1] - mxa);
                float p2 = __builtin_amdgcn_exp2f(sa[jf][2] - mxa);
                float p3 = __builtin_amdgcn_exp2f(sa[jf][3] - mxa);
                sum_a += (p0 + p1) + (p2 + p3);
                unsigned int* dst = (unsigned int*)(&Pl[wave][li][jf2 * 16 + lg * 4]);
                dst[0] = pk2bf(p0, p1); dst[1] = pk2bf(p2, p3);
            }
            {
                bf16x8 pf = *(const bf16x8*)(&Pl[wave][li][lg * 8]);
                __builtin_amdgcn_s_setprio(1);
                oa0 = __builtin_amdgcn_mfma_f32_16x16x32_bf16(va, pf, oa0, 0, 0, 0);
                oa1 = __builtin_amdgcn_mfma_f32_16x16x32_bf16(vb, pf, oa1, 0, 0, 0);
                __builtin_amdgcn_s_setprio(0);
            }
            // row-group b (reuses va/vb registers and the same Pl slots; same-wave DS ops are in-order)
            #pragma unroll
            for (int jf2 = 0; jf2 < 2; ++jf2) {
                int jf = half * 2 + jf2;
                float p0 = __builtin_amdgcn_exp2f(sb[jf][0] - mxb);
                float p1 = __builtin_amdgcn_exp2f(sb[jf][1] - mxb);
                float p2 = __builtin_amdgcn_exp2f(sb[jf][2] - mxb);
                float p3 = __builtin_amdgcn_exp2f(sb[jf][3] - mxb);
                sum_b += (p0 + p1) + (p2 + p3);
                unsigned int* dst = (unsigned int*)(&Pl[wave][li][jf2 * 16 + lg * 4]);
                dst[0] = pk2bf(p0, p1); dst[1] = pk2bf(p2, p3);
            }
            {
                bf16x8 pf = *(const bf16x8*)(&Pl[wave][li][lg * 8]);
                __builtin_amdgcn_s_setprio(1);
                ob0 = __builtin_amdgcn_mfma_f32_16x16x32_bf16(va, pf, ob0, 0, 0, 0);
                ob1 = __builtin_amdgcn_mfma_f32_16x16x32_bf16(vb, pf, ob1, 0, 0, 0);
                __builtin_amdgcn_s_setprio(0);
            }
        }
    }
    sum_a += __shfl_xor(sum_a, 16, 64);
    sum_a += __shfl_xor(sum_a, 32, 64);
    sum_b += __shfl_xor(sum_b, 16, 64);
    sum_b += __shfl_xor(sum_b, 32, 64);
    float inva = 1.0f / sum_a, invb = 1.0f / sum_b;
    size_t orow_a = ((size_t)m * NRES + ia) * CCH + h * 32;
    size_t orow_b = ((size_t)m * NRES + ib) * CCH + h * 32;
    #pragma unroll
    for (int df = 0; df < 2; ++df) {
        int dcb = df * 16 + lg * 4;
        f32x4 o = df ? oa1 : oa0;
        u16x4 gv = *(const u16x4*)(qkvg + qrow_a + 384 + h * 32 + dcb);
        u16x4 ov;
        #pragma unroll
        for (int r = 0; r < 4; ++r) ov[r] = f2bf(o[r] * inva * bf2f(gv[r]));
        *(u16x4*)(opre + orow_a + dcb) = ov;
        o = df ? ob1 : ob0;
        gv = *(const u16x4*)(qkvg + qrow_b + 384 + h * 32 + dcb);
        #pragma unroll
        for (int r = 0; r < 4; ++r) ov[r] = f2bf(o[r] * invb * bf2f(gv[r]));
        *(u16x4*)(opre + orow_b + dcb) = ov;
    }
}

// ---------------- Kernel 4: out = opre @ wo + bo (f32 out; conflict-free B staging) ----------------
__global__ __launch_bounds__(256) void k_out(
    const unsigned short* __restrict__ opre, const float* __restrict__ wo,
    const float* __restrict__ bo, float* __restrict__ out)
{
    __shared__ unsigned short A[128][136];
    __shared__ unsigned short Bt[128][136];
    int m0 = blockIdx.x * 128;
    int t = threadIdx.x;
    #pragma unroll
    for (int it = 0; it < 8; ++it) {
        int idx = it * 256 + t;
        int row = idx >> 4, chunk = idx & 15;
        *(bf16x8*)(&A[row][chunk * 8]) = *(const bf16x8*)(opre + (size_t)(m0 + row) * CCH + chunk * 8);
    }
    {
        int n = t & 127, p = t >> 7;
        const float* col = wo + n;
        #pragma unroll
        for (int q = 0; q < 8; ++q) {
            int k0 = p * 64 + q * 8;
            union { unsigned int u[4]; bf16x8 v; } pk;
            #pragma unroll
            for (int z = 0; z < 4; ++z)
                pk.u[z] = pk2bf(col[(size_t)(k0 + 2 * z) * 128], col[(size_t)(k0 + 2 * z + 1) * 128]);
            *(bf16x8*)(&Bt[n][k0]) = pk.v;
        }
    }
    __syncthreads();
    int wave = t >> 6, lane = t & 63;
    int wr = (wave >> 1) * 64, wc = (wave & 1) * 64;
    int li = lane & 15, lk = (lane >> 4) * 8;
    f32x4 acc[4][4] = {};
    #pragma unroll
    for (int kk = 0; kk < 4; ++kk) {
        bf16x8 af[4], bfr[4];
        #pragma unroll
        for (int i = 0; i < 4; ++i) af[i] = *(const bf16x8*)(&A[wr + i * 16 + li][kk * 32 + lk]);
        #pragma unroll
        for (int j = 0; j < 4; ++j) bfr[j] = *(const bf16x8*)(&Bt[wc + j * 16 + li][kk * 32 + lk]);
        __builtin_amdgcn_s_setprio(1);
        #pragma unroll
        for (int i = 0; i < 4; ++i)
            #pragma unroll
            for (int j = 0; j < 4; ++j)
                acc[i][j] = __builtin_amdgcn_mfma_f32_16x16x32_bf16(af[i], bfr[j], acc[i][j], 0, 0, 0);
        __builtin_amdgcn_s_setprio(0);
    }
    int rbase = (lane >> 4) * 4;
    #pragma unroll
    for (int i = 0; i < 4; ++i) {
        #pragma unroll
        for (int j = 0; j < 4; ++j) {
            int col = wc + j * 16 + li;
            #pragma unroll
            for (int r = 0; r < 4; ++r) {
                int grow = m0 + wr + i * 16 + rbase + r;
                out[(size_t)grow * CCH + col] = acc[i][j][r] + bo[col];
            }
        }
    }
}

extern "C" void kernel_launch(void* const* d_in, const int* in_sizes, int n_in,
                              void* d_out, int out_size, void* d_ws, size_t ws_size,
                              hipStream_t stream) {
    const float* x2d  = (const float*)d_in[0];
    const float* mask = (const float*)d_in[1];
    const float* ln_g = (const float*)d_in[2];
    const float* ln_b = (const float*)d_in[3];
    const float* wq   = (const float*)d_in[4];
    const float* wk   = (const float*)d_in[5];
    const float* wv   = (const float*)d_in[6];
    const float* wb   = (const float*)d_in[7];
    const float* wg   = (const float*)d_in[8];
    const float* bg   = (const float*)d_in[9];
    const float* wo   = (const float*)d_in[10];
    const float* bo   = (const float*)d_in[11];
    float* out = (float*)d_out;

    char* ws = (char*)d_ws;
    unsigned short* xn    = (unsigned short*)ws;                                 // 26,214,400 B (reused as opre)
    unsigned short* qkvg  = (unsigned short*)(ws + 26214400);                    // 104,857,600 B
    float*          bterm = (float*)(ws + 26214400 + 104857600);                 // 1,638,400 B
    unsigned short* opre  = xn;

    if (ws_size < (size_t)(26214400 + 104857600 + 1638400)) return;

    k_ln_bias<<<25600, 256, 0, stream>>>(x2d, ln_g, ln_b, wb, xn, bterm);
    k_proj<<<dim3(800, 4), 256, 0, stream>>>(xn, wq, wk, wv, wg, bg, qkvg);
    k_attn<<<1280, ABLK, 0, stream>>>(qkvg, bterm, mask, opre);
    k_out<<<800, 256, 0, stream>>>(opre, wo, bo, out);
}